// Round 2
// baseline (18315.157 us; speedup 1.0000x reference)
//
#include <hip/hip_runtime.h>
#include <math.h>

#define DD 128      // hidden dim
#define ANND 64     // annotation dim
#define NSTEPS 5
#define NTYPES 4
#define NCLS 10

__device__ __forceinline__ float dot4(float4 a, float4 b) {
  return a.x*b.x + a.y*b.y + a.z*b.z + a.w*b.w;
}

// h[n][d] = d < 64 ? annotation[n][d] : 0
__global__ void k_init_h(const float* __restrict__ ann, float* __restrict__ h, int n) {
  int idx = blockIdx.x * blockDim.x + threadIdx.x;
  if (idx >= n * DD) return;
  int node = idx >> 7, d = idx & 127;
  h[idx] = (d < ANND) ? ann[node * ANND + d] : 0.0f;
}

// ---------- CSR build (by dst), once per launch ----------
__global__ void k_deg(const int* __restrict__ dst, int* __restrict__ deg, int e) {
  int i = blockIdx.x * blockDim.x + threadIdx.x;
  if (i < e) atomicAdd(&deg[dst[i]], 1);
}

// single-block exclusive scan over deg[0..n) -> base[0..n]
__global__ __launch_bounds__(1024) void k_scan(const int* __restrict__ deg,
    int* __restrict__ base, int n) {
  __shared__ int part[1024];
  int t = threadIdx.x;
  int chunk = (n + 1023) >> 10;
  int s = t * chunk, e = min(n, s + chunk);
  int sum = 0;
  for (int i = s; i < e; ++i) sum += deg[i];
  part[t] = sum;
  __syncthreads();
  int own = sum;
  for (int off = 1; off < 1024; off <<= 1) {
    int v = (t >= off) ? part[t - off] : 0;
    __syncthreads();
    part[t] += v;
    __syncthreads();
  }
  int run = part[t] - own;                 // exclusive prefix of this chunk
  for (int i = s; i < e; ++i) { base[i] = run; run += deg[i]; }
  if (s < n && e == n) base[n] = run;      // total = E
}

__global__ void k_place(const int* __restrict__ src, const int* __restrict__ dst,
    const int* __restrict__ et, const int* __restrict__ base, int* __restrict__ cursor,
    int* __restrict__ csrc, int* __restrict__ cet, int e) {
  int i = blockIdx.x * blockDim.x + threadIdx.x;
  if (i >= e) return;
  int d = dst[i];
  int pos = base[d] + atomicAdd(&cursor[d], 1);
  csrc[pos] = src[i];
  cet[pos]  = et[i];
}

// ---------- out[n][o] = sum_d h[n][d] * W[o][d] + bias[o] ----------
// 64 nodes x 128 outs, 256 thr, 4x8 micro-tile, K chunked by 32, h+W in LDS.
// hs: stride 36 (2-way conflict = free). wsm: stride 32 + XOR swizzle on f4 col.
__global__ __launch_bounds__(256, 4) void k_lin(const float* __restrict__ h,
    const float* __restrict__ W, const float* __restrict__ bias,
    float* __restrict__ out, int n) {
  __shared__ float hs[64 * 36];
  __shared__ float wsm[128 * 32];
  int tid = threadIdx.x;
  int nb = blockIdx.x * 64;
  int tx = tid & 15, ty = tid >> 4;
  float acc[4][8];
  #pragma unroll
  for (int j = 0; j < 8; ++j) {
    float bv = bias[tx * 8 + j];
    #pragma unroll
    for (int i = 0; i < 4; ++i) acc[i][j] = bv;
  }
  for (int kc = 0; kc < 128; kc += 32) {
    __syncthreads();
    #pragma unroll
    for (int i = 0; i < 2; ++i) {          // stage h tile chunk: 64x32
      int f4 = tid + i * 256;
      int row = f4 >> 3, cc = f4 & 7;
      float4 v = make_float4(0.f, 0.f, 0.f, 0.f);
      if (nb + row < n)
        v = *reinterpret_cast<const float4*>(h + (size_t)(nb + row) * DD + kc + cc * 4);
      *reinterpret_cast<float4*>(hs + row * 36 + cc * 4) = v;
    }
    #pragma unroll
    for (int i = 0; i < 4; ++i) {          // stage W chunk swizzled: 128x32
      int f4 = tid + i * 256;
      int row = f4 >> 3, cc = f4 & 7;
      int cs = cc ^ ((row >> 3) & 7);
      float4 v = *reinterpret_cast<const float4*>(W + (size_t)row * DD + kc + cc * 4);
      *reinterpret_cast<float4*>(wsm + row * 32 + cs * 4) = v;
    }
    __syncthreads();
    #pragma unroll
    for (int k4 = 0; k4 < 8; ++k4) {
      float4 a4[4], w4[8];
      #pragma unroll
      for (int i = 0; i < 4; ++i)
        a4[i] = *reinterpret_cast<const float4*>(hs + (ty * 4 + i) * 36 + k4 * 4);
      #pragma unroll
      for (int j = 0; j < 8; ++j)
        w4[j] = *reinterpret_cast<const float4*>(wsm + (tx * 8 + j) * 32 + ((k4 ^ (tx & 7)) * 4));
      #pragma unroll
      for (int i = 0; i < 4; ++i)
        #pragma unroll
        for (int j = 0; j < 8; ++j)
          acc[i][j] += dot4(a4[i], w4[j]);
    }
  }
  #pragma unroll
  for (int i = 0; i < 4; ++i) {
    int node = nb + ty * 4 + i;
    if (node < n) {
      float* o = out + (size_t)node * DD + tx * 8;
      *reinterpret_cast<float4*>(o)     = make_float4(acc[i][0], acc[i][1], acc[i][2], acc[i][3]);
      *reinterpret_cast<float4*>(o + 4) = make_float4(acc[i][4], acc[i][5], acc[i][6], acc[i][7]);
    }
  }
}

// ---------- a[node] (+)= sum over in-edges of type ktype of tmp[src] ----------
__global__ void k_agg(const float* __restrict__ tmp, const int* __restrict__ base,
    const int* __restrict__ csrc, const int* __restrict__ cet,
    float* __restrict__ a, int n, int ktype, int first) {
  int node = blockIdx.x * 2 + (threadIdx.x >> 7);
  int c = threadIdx.x & 127;
  if (node >= n) return;
  int s = base[node], e = base[node + 1];
  float acc = first ? 0.f : a[(size_t)node * DD + c];
  for (int i = s; i < e; ++i) {
    if (cet[i] == ktype)
      acc += tmp[(size_t)csrc[i] * DD + c];
  }
  a[(size_t)node * DD + c] = acc;
}

// ---------- fused GRU, 64 nodes/block, 16 nodes/thread, 4 accumulators ----------
__global__ __launch_bounds__(512, 4) void k_gru(const float* __restrict__ a,
    float* __restrict__ h, const float* __restrict__ Wih, const float* __restrict__ Whh,
    const float* __restrict__ bih, const float* __restrict__ bhh, int n) {
  __shared__ float as[64 * 128];   // 32 KiB
  __shared__ float hs[64 * 128];   // 32 KiB
  int tid = threadIdx.x;
  int nb = blockIdx.x * 64;
  #pragma unroll
  for (int i = 0; i < 4; ++i) {
    int f4 = tid + i * 512;
    int row = f4 >> 5, c4 = (f4 & 31) * 4;
    float4 va = make_float4(0.f, 0.f, 0.f, 0.f), vh = va;
    if (nb + row < n) {
      va = *reinterpret_cast<const float4*>(a + (size_t)(nb + row) * DD + c4);
      vh = *reinterpret_cast<const float4*>(h + (size_t)(nb + row) * DD + c4);
    }
    *reinterpret_cast<float4*>(as + row * DD + c4) = va;
    *reinterpret_cast<float4*>(hs + row * DD + c4) = vh;
  }
  __syncthreads();
  int d = tid & 127, nl = tid >> 7;     // nl in 0..3, 16 nodes each
  float sr[16], sz[16], gn[16], hn[16];
  {
    float b0 = bih[d] + bhh[d];
    float b1 = bih[DD + d] + bhh[DD + d];
    float b2 = bih[2 * DD + d];
    float b3 = bhh[2 * DD + d];
    #pragma unroll
    for (int i = 0; i < 16; ++i) { sr[i] = b0; sz[i] = b1; gn[i] = b2; hn[i] = b3; }
  }
  const float* wr_i = Wih + (size_t)d * DD;
  const float* wz_i = Wih + (size_t)(DD + d) * DD;
  const float* wn_i = Wih + (size_t)(2 * DD + d) * DD;
  const float* wr_h = Whh + (size_t)d * DD;
  const float* wz_h = Whh + (size_t)(DD + d) * DD;
  const float* wn_h = Whh + (size_t)(2 * DD + d) * DD;
  int rbase = nl * 16;
  for (int kc = 0; kc < DD; kc += 4) {
    float4 wir = *reinterpret_cast<const float4*>(wr_i + kc);
    float4 wiz = *reinterpret_cast<const float4*>(wz_i + kc);
    float4 win = *reinterpret_cast<const float4*>(wn_i + kc);
    float4 whr = *reinterpret_cast<const float4*>(wr_h + kc);
    float4 whz = *reinterpret_cast<const float4*>(wz_h + kc);
    float4 whn = *reinterpret_cast<const float4*>(wn_h + kc);
    #pragma unroll
    for (int i = 0; i < 16; ++i) {
      float4 a4 = *reinterpret_cast<const float4*>(as + (rbase + i) * DD + kc);
      float4 h4 = *reinterpret_cast<const float4*>(hs + (rbase + i) * DD + kc);
      sr[i] += dot4(a4, wir) + dot4(h4, whr);
      sz[i] += dot4(a4, wiz) + dot4(h4, whz);
      gn[i] += dot4(a4, win);
      hn[i] += dot4(h4, whn);
    }
  }
  #pragma unroll
  for (int i = 0; i < 16; ++i) {
    int row = rbase + i, node = nb + row;
    if (node < n) {
      float r = 1.f / (1.f + expf(-sr[i]));
      float z = 1.f / (1.f + expf(-sz[i]));
      float nt = tanhf(gn[i] + r * hn[i]);
      h[(size_t)node * DD + d] = (1.f - z) * nt + z * hs[row * DD + d];
    }
  }
}

// gate[n] = dot([h[n] | ann[n]], gate_w) + gate_b    (one wave per node)
__global__ void k_gate(const float* __restrict__ h, const float* __restrict__ ann,
    const float* __restrict__ gw, const float* __restrict__ gb,
    float* __restrict__ gate, int n) {
  int gt = blockIdx.x * blockDim.x + threadIdx.x;
  int wv = gt >> 6;
  int lane = threadIdx.x & 63;
  if (wv >= n) return;
  float p = h[(size_t)wv * DD + lane] * gw[lane]
          + h[(size_t)wv * DD + 64 + lane] * gw[64 + lane]
          + ann[(size_t)wv * ANND + lane] * gw[128 + lane];
  for (int off = 32; off; off >>= 1) p += __shfl_down(p, off);
  if (lane == 0) gate[wv] = p + gb[0];
}

__global__ void k_bounds(const int* __restrict__ n2g, int* __restrict__ startg,
    int* __restrict__ endg, int n) {
  int i = blockIdx.x * blockDim.x + threadIdx.x;
  if (i >= n) return;
  int g = n2g[i];
  atomicMin(&startg[g], i);
  atomicMax(&endg[g], i + 1);
}

// per-graph segment softmax + attention readout
__global__ __launch_bounds__(256) void k_pool(const float* __restrict__ gate,
    float* __restrict__ ex, const float* __restrict__ h, const float* __restrict__ ann,
    const int* __restrict__ startg, const int* __restrict__ endg,
    float* __restrict__ readout, int n) {
  __shared__ float red[256];
  __shared__ float m_s, den_s;
  int g = blockIdx.x;
  int s = startg[g], e = endg[g];
  int tid = threadIdx.x;
  float m = -1e30f;
  for (int i = s + tid; i < e; i += 256) m = fmaxf(m, gate[i]);
  red[tid] = m; __syncthreads();
  for (int off = 128; off; off >>= 1) {
    if (tid < off) red[tid] = fmaxf(red[tid], red[tid + off]);
    __syncthreads();
  }
  if (tid == 0) m_s = red[0];
  __syncthreads();
  m = m_s;
  float sum = 0.f;
  for (int i = s + tid; i < e; i += 256) {
    float v = expf(gate[i] - m);
    ex[i] = v;
    sum += v;
  }
  red[tid] = sum; __syncthreads();
  for (int off = 128; off; off >>= 1) {
    if (tid < off) red[tid] += red[tid + off];
    __syncthreads();
  }
  if (tid == 0) den_s = red[0];
  __syncthreads();
  float inv = (s < e) ? 1.f / den_s : 0.f;
  for (int d = tid; d < DD + ANND; d += 256) {
    float acc = 0.f;
    for (int i = s; i < e; ++i) {
      float f = (d < DD) ? h[(size_t)i * DD + d] : ann[(size_t)i * ANND + (d - DD)];
      acc += ex[i] * f;
    }
    readout[g * (DD + ANND) + d] = acc * inv;
  }
}

// logits, argmax preds, NLL loss. out[0]=loss, out[1+g]=pred_g (as float)
__global__ void k_logits(const float* __restrict__ readout, const float* __restrict__ ow,
    const float* __restrict__ ob, const int* __restrict__ labels,
    float* __restrict__ out, int B) {
  __shared__ float lsum[64];
  int g = threadIdx.x;
  float loss_c = 0.f;
  if (g < B) {
    float lg[NCLS];
    float mx = -1e30f;
    int best = 0;
    for (int c = 0; c < NCLS; ++c) {
      float acc = ob[c];
      const float* r = readout + g * (DD + ANND);
      const float* w = ow + c * (DD + ANND);
      for (int d = 0; d < DD + ANND; ++d) acc += r[d] * w[d];
      lg[c] = acc;
      if (acc > mx) { mx = acc; best = c; }
    }
    float se = 0.f;
    for (int c = 0; c < NCLS; ++c) se += expf(lg[c] - mx);
    float lse = mx + logf(se);
    loss_c = -(lg[labels[g]] - lse);
    out[1 + g] = (float)best;
  }
  lsum[threadIdx.x] = loss_c;
  __syncthreads();
  for (int off = 32; off; off >>= 1) {
    if (threadIdx.x < off) lsum[threadIdx.x] += lsum[threadIdx.x + off];
    __syncthreads();
  }
  if (threadIdx.x == 0) out[0] = lsum[0] / (float)B;
}

extern "C" void kernel_launch(void* const* d_in, const int* in_sizes, int n_in,
                              void* d_out, int out_size, void* d_ws, size_t ws_size,
                              hipStream_t stream) {
  const float* annotation = (const float*)d_in[0];
  const int*   src        = (const int*)d_in[1];
  const int*   dst        = (const int*)d_in[2];
  const int*   et         = (const int*)d_in[3];
  const int*   n2g        = (const int*)d_in[4];
  const int*   labels     = (const int*)d_in[5];
  const float* W_lin      = (const float*)d_in[6];
  const float* b_lin      = (const float*)d_in[7];
  const float* W_ih       = (const float*)d_in[8];
  const float* W_hh       = (const float*)d_in[9];
  const float* b_ih       = (const float*)d_in[10];
  const float* b_hh       = (const float*)d_in[11];
  const float* gate_w     = (const float*)d_in[12];
  const float* gate_b     = (const float*)d_in[13];
  const float* out_w      = (const float*)d_in[14];
  const float* out_b      = (const float*)d_in[15];

  int N = in_sizes[0] / ANND;
  int E = in_sizes[1];
  int B = in_sizes[5];

  char* ws = (char*)d_ws;
  float* h    = (float*)ws; ws += (size_t)N * DD * 4;
  float* tmp  = (float*)ws; ws += (size_t)N * DD * 4;
  float* a    = (float*)ws; ws += (size_t)N * DD * 4;
  float* gate = (float*)ws; ws += (size_t)N * 4;
  float* ex   = (float*)ws; ws += (size_t)N * 4;
  float* readout = (float*)ws; ws += (size_t)B * (DD + ANND) * 4;
  int* startg = (int*)ws; ws += (size_t)B * 4;
  int* endg   = (int*)ws; ws += (size_t)B * 4;
  int* deg    = (int*)ws; ws += (size_t)N * 4;
  int* base   = (int*)ws; ws += (size_t)(N + 1) * 4;
  int* cursor = (int*)ws; ws += (size_t)N * 4;
  int* csrc   = (int*)ws; ws += (size_t)E * 4;
  int* cet    = (int*)ws; ws += (size_t)E * 4;

  k_init_h<<<(N * DD + 255) / 256, 256, 0, stream>>>(annotation, h, N);

  // CSR build (once per launch)
  hipMemsetAsync(deg, 0, (size_t)N * 4, stream);
  hipMemsetAsync(cursor, 0, (size_t)N * 4, stream);
  k_deg<<<(E + 255) / 256, 256, 0, stream>>>(dst, deg, E);
  k_scan<<<1, 1024, 0, stream>>>(deg, base, N);
  k_place<<<(E + 255) / 256, 256, 0, stream>>>(src, dst, et, base, cursor, csrc, cet, E);

  hipMemsetAsync(startg, 0x7f, (size_t)B * 4, stream);
  hipMemsetAsync(endg, 0, (size_t)B * 4, stream);
  k_bounds<<<(N + 255) / 256, 256, 0, stream>>>(n2g, startg, endg, N);

  for (int s = 0; s < NSTEPS; ++s) {
    for (int k = 0; k < NTYPES; ++k) {
      k_lin<<<(N + 63) / 64, 256, 0, stream>>>(
          h, W_lin + (size_t)k * DD * DD, b_lin + (size_t)k * DD, tmp, N);
      k_agg<<<(N + 1) / 2, 256, 0, stream>>>(tmp, base, csrc, cet, a, N, k, k == 0);
    }
    k_gru<<<(N + 63) / 64, 512, 0, stream>>>(a, h, W_ih, W_hh, b_ih, b_hh, N);
  }

  k_gate<<<(N * 64 + 255) / 256, 256, 0, stream>>>(h, annotation, gate_w, gate_b, gate, N);
  k_pool<<<B, 256, 0, stream>>>(gate, ex, h, annotation, startg, endg, readout, N);
  k_logits<<<1, 64, 0, stream>>>(readout, out_w, out_b, labels, (float*)d_out, B);
}

// Round 4
// 4097.812 us; speedup vs baseline: 4.4695x; 4.4695x over previous
//
#include <hip/hip_runtime.h>
#include <math.h>

#define DD 128      // hidden dim
#define ANND 64     // annotation dim
#define NSTEPS 5
#define NTYPES 4
#define NCLS 10
#define CHUNK 6272  // nodes per pipeline chunk (multiple of 64)

typedef __attribute__((ext_vector_type(8))) short short8v;  // 8 bf16
typedef __attribute__((ext_vector_type(4))) float f32x4;

// split fp32 into hi+lo bf16 (RNE both)
__device__ __forceinline__ void split2(float x, unsigned short& hi, unsigned short& lo) {
  unsigned u = __float_as_uint(x);
  unsigned hb = (u + 0x7FFFu + ((u >> 16) & 1u)) >> 16;
  hi = (unsigned short)hb;
  float r = x - __uint_as_float(hb << 16);
  unsigned v = __float_as_uint(r);
  lo = (unsigned short)((v + 0x7FFFu + ((v >> 16) & 1u)) >> 16);
}

__device__ __forceinline__ float bf2f(unsigned short u) {
  return __uint_as_float(((unsigned)u) << 16);
}
__device__ __forceinline__ float rec2(const unsigned short* hi, const unsigned short* lo, size_t i) {
  return bf2f(hi[i]) + bf2f(lo[i]);
}

// h = [ann | 0] as split planes; zero-fill padded rows [n, npad)
__global__ void k_init(const float* __restrict__ ann,
    unsigned short* __restrict__ hhi, unsigned short* __restrict__ hlo, int n, int npad) {
  int idx = blockIdx.x * blockDim.x + threadIdx.x;
  if (idx >= npad * DD) return;
  int node = idx >> 7, d = idx & 127;
  float v = (node < n && d < ANND) ? ann[node * ANND + d] : 0.0f;
  unsigned short hi, lo; split2(v, hi, lo);
  hhi[idx] = hi; hlo[idx] = lo;
}

// ---------- CSR build (by dst), once per launch ----------
__global__ void k_deg(const int* __restrict__ dst, int* __restrict__ deg, int e) {
  int i = blockIdx.x * blockDim.x + threadIdx.x;
  if (i < e) atomicAdd(&deg[dst[i]], 1);
}

__global__ void k_deg4(const int* __restrict__ dst, const int* __restrict__ et,
    int* __restrict__ deg4, int e) {
  int i = blockIdx.x * blockDim.x + threadIdx.x;
  if (i < e) atomicAdd(&deg4[dst[i] * 4 + et[i]], 1);
}

__global__ __launch_bounds__(1024) void k_scan(const int* __restrict__ deg,
    int* __restrict__ base, int n) {
  __shared__ int part[1024];
  int t = threadIdx.x;
  int chunk = (n + 1023) >> 10;
  int s = t * chunk, e = min(n, s + chunk);
  int sum = 0;
  for (int i = s; i < e; ++i) sum += deg[i];
  part[t] = sum;
  __syncthreads();
  int own = sum;
  for (int off = 1; off < 1024; off <<= 1) {
    int v = (t >= off) ? part[t - off] : 0;
    __syncthreads();
    part[t] += v;
    __syncthreads();
  }
  int run = part[t] - own;
  for (int i = s; i < e; ++i) { base[i] = run; run += deg[i]; }
  if (s < n && e == n) base[n] = run;
}

__global__ void k_place(const int* __restrict__ src, const int* __restrict__ dst,
    const int* __restrict__ et, const int* __restrict__ base, int* __restrict__ cursor,
    int* __restrict__ csrc, int* __restrict__ cet, int e) {
  int i = blockIdx.x * blockDim.x + threadIdx.x;
  if (i >= e) return;
  int d = dst[i];
  int pos = base[d] + atomicAdd(&cursor[d], 1);
  csrc[pos] = src[i];
  cet[pos]  = et[i];
}

// ---------- per-type neighbor sums for one chunk ----------
// A3[local][k*128+c] = sum_{type-k in-edges of node nbase+local} h[src][c]
__global__ void k_aggh(const unsigned short* __restrict__ hhi,
    const unsigned short* __restrict__ hlo, const int* __restrict__ base,
    const int* __restrict__ csrc, const int* __restrict__ cet,
    unsigned short* __restrict__ A3hi, unsigned short* __restrict__ A3lo,
    int nbase, int cc) {
  int local = blockIdx.x * 2 + (threadIdx.x >> 7);
  int c = threadIdx.x & 127;
  if (local >= cc) return;
  int node = nbase + local;
  int s = base[node], e = base[node + 1];
  float s0 = 0.f, s1 = 0.f, s2 = 0.f, s3 = 0.f;
  for (int i = s; i < e; ++i) {
    float v = rec2(hhi, hlo, (size_t)csrc[i] * DD + c);
    int t = cet[i];                       // wave-uniform branch
    if (t == 0) s0 += v; else if (t == 1) s1 += v;
    else if (t == 2) s2 += v; else s3 += v;
  }
  size_t b = (size_t)local * 512 + c;
  unsigned short hi, lo;
  split2(s0, hi, lo); A3hi[b]       = hi; A3lo[b]       = lo;
  split2(s1, hi, lo); A3hi[b + 128] = hi; A3lo[b + 128] = lo;
  split2(s2, hi, lo); A3hi[b + 256] = hi; A3lo[b + 256] = lo;
  split2(s3, hi, lo); A3hi[b + 384] = hi; A3lo[b + 384] = lo;
}

// ---------- MFMA GEMM: C[n x O] = A[n x K](split) @ W[O x K](split)^T ----------
// MODE 0: C fp32 (ldc), bias[col].  MODE 1: deg-bias (b_lin, deg4) + split store to Chi/Clo (ld 128).
template<int MODE>
__global__ __launch_bounds__(256) void k_gemm(
    const unsigned short* __restrict__ Ahi, const unsigned short* __restrict__ Alo,
    int lda, int K,
    const unsigned short* __restrict__ Whi, const unsigned short* __restrict__ Wlo,
    const float* __restrict__ bias, const int* __restrict__ deg4,
    float* __restrict__ C, int ldc,
    unsigned short* __restrict__ Chi, unsigned short* __restrict__ Clo, int n) {
  int wid = threadIdx.x >> 6, lane = threadIdx.x & 63;
  int rowbase = blockIdx.x * 64 + (wid >> 1) * 32;
  int colbase = blockIdx.y * 64 + (wid & 1) * 32;
  int lr = lane & 15, lk = lane >> 4;
  f32x4 acc[2][2];
  #pragma unroll
  for (int nn = 0; nn < 2; ++nn) {
    float bv = (MODE == 0) ? bias[colbase + nn * 16 + lr] : 0.f;
    #pragma unroll
    for (int mm = 0; mm < 2; ++mm) acc[mm][nn] = (f32x4){bv, bv, bv, bv};
  }
  for (int k0 = 0; k0 < K; k0 += 32) {
    int koff = k0 + lk * 8;
    short8v ah[2], al[2], bh[2], bl[2];
    #pragma unroll
    for (int mm = 0; mm < 2; ++mm) {
      size_t off = (size_t)(rowbase + mm * 16 + lr) * lda + koff;
      ah[mm] = *(const short8v*)(Ahi + off);
      al[mm] = *(const short8v*)(Alo + off);
    }
    #pragma unroll
    for (int nn = 0; nn < 2; ++nn) {
      size_t off = (size_t)(colbase + nn * 16 + lr) * K + koff;
      bh[nn] = *(const short8v*)(Whi + off);
      bl[nn] = *(const short8v*)(Wlo + off);
    }
    #pragma unroll
    for (int mm = 0; mm < 2; ++mm)
      #pragma unroll
      for (int nn = 0; nn < 2; ++nn) {
        acc[mm][nn] = __builtin_amdgcn_mfma_f32_16x16x32_bf16(ah[mm], bh[nn], acc[mm][nn], 0, 0, 0);
        acc[mm][nn] = __builtin_amdgcn_mfma_f32_16x16x32_bf16(ah[mm], bl[nn], acc[mm][nn], 0, 0, 0);
        acc[mm][nn] = __builtin_amdgcn_mfma_f32_16x16x32_bf16(al[mm], bh[nn], acc[mm][nn], 0, 0, 0);
      }
  }
  #pragma unroll
  for (int mm = 0; mm < 2; ++mm) {
    #pragma unroll
    for (int j = 0; j < 4; ++j) {
      int row = rowbase + mm * 16 + lk * 4 + j;
      if (row < n) {
        if (MODE == 0) {
          #pragma unroll
          for (int nn = 0; nn < 2; ++nn)
            C[(size_t)row * ldc + colbase + nn * 16 + lr] = acc[mm][nn][j];
        } else {
          int4 dg = *(const int4*)(deg4 + (size_t)row * 4);
          #pragma unroll
          for (int nn = 0; nn < 2; ++nn) {
            int col = colbase + nn * 16 + lr;
            float v = acc[mm][nn][j] + dg.x * bias[col] + dg.y * bias[128 + col]
                    + dg.z * bias[256 + col] + dg.w * bias[384 + col];
            unsigned short hi, lo; split2(v, hi, lo);
            Chi[(size_t)row * DD + col] = hi;
            Clo[(size_t)row * DD + col] = lo;
          }
        }
      }
    }
  }
}

// ---------- GRU elementwise for one chunk: h_nxt = GRU(gi, gh, h_cur) ----------
__global__ void k_gruel(const float* __restrict__ gi, const float* __restrict__ gh,
    const unsigned short* __restrict__ hchi, const unsigned short* __restrict__ hclo,
    unsigned short* __restrict__ hnhi, unsigned short* __restrict__ hnlo,
    int nbase, int cc) {
  int idx = blockIdx.x * blockDim.x + threadIdx.x;
  if (idx >= cc * DD) return;
  int local = idx >> 7, d = idx & 127;
  size_t b = (size_t)local * 384;
  float ir = gi[b + d], iz = gi[b + 128 + d], inn = gi[b + 256 + d];
  float hr = gh[b + d], hz = gh[b + 128 + d], hn = gh[b + 256 + d];
  float r = 1.f / (1.f + expf(-(ir + hr)));
  float z = 1.f / (1.f + expf(-(iz + hz)));
  float nt = tanhf(inn + r * hn);
  size_t gidx = (size_t)(nbase + local) * DD + d;
  float hv = (1.f - z) * nt + z * rec2(hchi, hclo, gidx);
  unsigned short hi, lo; split2(hv, hi, lo);
  hnhi[gidx] = hi; hnlo[gidx] = lo;
}

// ---------- weight prep ----------
// WlinT[o][k*128+d] = W_lin[k][o][d], split
__global__ void k_repack_wlin(const float* __restrict__ W,
    unsigned short* __restrict__ hi_, unsigned short* __restrict__ lo_) {
  int idx = blockIdx.x * blockDim.x + threadIdx.x;
  if (idx >= 128 * 512) return;
  int o = idx >> 9, kd = idx & 511;
  int k = kd >> 7, d = kd & 127;
  float v = W[k * 16384 + o * 128 + d];
  unsigned short h, l; split2(v, h, l);
  hi_[idx] = h; lo_[idx] = l;
}

__global__ void k_splitw(const float* __restrict__ x,
    unsigned short* __restrict__ hi_, unsigned short* __restrict__ lo_, int n) {
  int i = blockIdx.x * blockDim.x + threadIdx.x;
  if (i >= n) return;
  unsigned short h, l; split2(x[i], h, l);
  hi_[i] = h; lo_[i] = l;
}

// ---------- readout ----------
__global__ void k_gate(const unsigned short* __restrict__ hhi,
    const unsigned short* __restrict__ hlo, const float* __restrict__ ann,
    const float* __restrict__ gw, const float* __restrict__ gb,
    float* __restrict__ gate, int n) {
  int gt = blockIdx.x * blockDim.x + threadIdx.x;
  int wv = gt >> 6;
  int lane = threadIdx.x & 63;
  if (wv >= n) return;
  float p = rec2(hhi, hlo, (size_t)wv * DD + lane) * gw[lane]
          + rec2(hhi, hlo, (size_t)wv * DD + 64 + lane) * gw[64 + lane]
          + ann[(size_t)wv * ANND + lane] * gw[128 + lane];
  for (int off = 32; off; off >>= 1) p += __shfl_down(p, off);
  if (lane == 0) gate[wv] = p + gb[0];
}

__global__ void k_bounds(const int* __restrict__ n2g, int* __restrict__ startg,
    int* __restrict__ endg, int n) {
  int i = blockIdx.x * blockDim.x + threadIdx.x;
  if (i >= n) return;
  int g = n2g[i];
  atomicMin(&startg[g], i);
  atomicMax(&endg[g], i + 1);
}

__global__ __launch_bounds__(256) void k_pool(const float* __restrict__ gate,
    float* __restrict__ ex, const unsigned short* __restrict__ hhi,
    const unsigned short* __restrict__ hlo, const float* __restrict__ ann,
    const int* __restrict__ startg, const int* __restrict__ endg,
    float* __restrict__ readout, int n) {
  __shared__ float red[256];
  __shared__ float m_s, den_s;
  int g = blockIdx.x;
  int s = startg[g], e = endg[g];
  int tid = threadIdx.x;
  float m = -1e30f;
  for (int i = s + tid; i < e; i += 256) m = fmaxf(m, gate[i]);
  red[tid] = m; __syncthreads();
  for (int off = 128; off; off >>= 1) {
    if (tid < off) red[tid] = fmaxf(red[tid], red[tid + off]);
    __syncthreads();
  }
  if (tid == 0) m_s = red[0];
  __syncthreads();
  m = m_s;
  float sum = 0.f;
  for (int i = s + tid; i < e; i += 256) {
    float v = expf(gate[i] - m);
    ex[i] = v;
    sum += v;
  }
  red[tid] = sum; __syncthreads();
  for (int off = 128; off; off >>= 1) {
    if (tid < off) red[tid] += red[tid + off];
    __syncthreads();
  }
  if (tid == 0) den_s = red[0];
  __syncthreads();
  float inv = (s < e) ? 1.f / den_s : 0.f;
  for (int d = tid; d < DD + ANND; d += 256) {
    float acc = 0.f;
    for (int i = s; i < e; ++i) {
      float f = (d < DD) ? rec2(hhi, hlo, (size_t)i * DD + d)
                         : ann[(size_t)i * ANND + (d - DD)];
      acc += ex[i] * f;
    }
    readout[g * (DD + ANND) + d] = acc * inv;
  }
}

__global__ void k_logits(const float* __restrict__ readout, const float* __restrict__ ow,
    const float* __restrict__ ob, const int* __restrict__ labels,
    float* __restrict__ out, int B) {
  __shared__ float lsum[64];
  int g = threadIdx.x;
  float loss_c = 0.f;
  if (g < B) {
    float lg[NCLS];
    float mx = -1e30f;
    int best = 0;
    for (int c = 0; c < NCLS; ++c) {
      float acc = ob[c];
      const float* r = readout + g * (DD + ANND);
      const float* w = ow + c * (DD + ANND);
      for (int d = 0; d < DD + ANND; ++d) acc += r[d] * w[d];
      lg[c] = acc;
      if (acc > mx) { mx = acc; best = c; }
    }
    float se = 0.f;
    for (int c = 0; c < NCLS; ++c) se += expf(lg[c] - mx);
    float lse = mx + logf(se);
    loss_c = -(lg[labels[g]] - lse);
    out[1 + g] = (float)best;
  }
  lsum[threadIdx.x] = loss_c;
  __syncthreads();
  for (int off = 32; off; off >>= 1) {
    if (threadIdx.x < off) lsum[threadIdx.x] += lsum[threadIdx.x + off];
    __syncthreads();
  }
  if (threadIdx.x == 0) out[0] = lsum[0] / (float)B;
}

extern "C" void kernel_launch(void* const* d_in, const int* in_sizes, int n_in,
                              void* d_out, int out_size, void* d_ws, size_t ws_size,
                              hipStream_t stream) {
  const float* annotation = (const float*)d_in[0];
  const int*   src        = (const int*)d_in[1];
  const int*   dst        = (const int*)d_in[2];
  const int*   et         = (const int*)d_in[3];
  const int*   n2g        = (const int*)d_in[4];
  const int*   labels     = (const int*)d_in[5];
  const float* W_lin      = (const float*)d_in[6];
  const float* b_lin      = (const float*)d_in[7];
  const float* W_ih       = (const float*)d_in[8];
  const float* W_hh       = (const float*)d_in[9];
  const float* b_ih       = (const float*)d_in[10];
  const float* b_hh       = (const float*)d_in[11];
  const float* gate_w     = (const float*)d_in[12];
  const float* gate_b     = (const float*)d_in[13];
  const float* out_w      = (const float*)d_in[14];
  const float* out_b      = (const float*)d_in[15];

  int N = in_sizes[0] / ANND;
  int E = in_sizes[1];
  int B = in_sizes[5];
  int Np = (N + 63) & ~63;

  char* wsP = (char*)d_ws;
  auto alloc = [&](size_t bytes) -> void* {
    void* p = (void*)wsP;
    wsP += (bytes + 255) & ~(size_t)255;
    return p;
  };
  // ping-pong h split planes (Np rows each)
  unsigned short* hP_hi[2], *hP_lo[2];
  hP_hi[0] = (unsigned short*)alloc((size_t)Np * DD * 2);
  hP_lo[0] = (unsigned short*)alloc((size_t)Np * DD * 2);
  hP_hi[1] = (unsigned short*)alloc((size_t)Np * DD * 2);
  hP_lo[1] = (unsigned short*)alloc((size_t)Np * DD * 2);
  // per-chunk buffers (reused)
  unsigned short* A3hi = (unsigned short*)alloc((size_t)CHUNK * 512 * 2);
  unsigned short* A3lo = (unsigned short*)alloc((size_t)CHUNK * 512 * 2);
  unsigned short* a_hi = (unsigned short*)alloc((size_t)CHUNK * DD * 2);
  unsigned short* a_lo = (unsigned short*)alloc((size_t)CHUNK * DD * 2);
  float* gi  = (float*)alloc((size_t)CHUNK * 384 * 4);
  float* gh  = (float*)alloc((size_t)CHUNK * 384 * 4);
  // small persistent
  float* gate = (float*)alloc((size_t)N * 4);
  float* ex   = (float*)alloc((size_t)N * 4);
  float* readout = (float*)alloc((size_t)B * (DD + ANND) * 4);
  int* startg = (int*)alloc((size_t)B * 4);
  int* endg   = (int*)alloc((size_t)B * 4);
  int* deg    = (int*)alloc((size_t)N * 4);
  int* base   = (int*)alloc((size_t)(N + 1) * 4);
  int* cursor = (int*)alloc((size_t)N * 4);
  int* deg4   = (int*)alloc((size_t)N * 4 * 4);
  int* csrc   = (int*)alloc((size_t)E * 4);
  int* cet    = (int*)alloc((size_t)E * 4);
  unsigned short* WlT_hi = (unsigned short*)alloc(128 * 512 * 2);
  unsigned short* WlT_lo = (unsigned short*)alloc(128 * 512 * 2);
  unsigned short* Wih_hi = (unsigned short*)alloc(384 * 128 * 2);
  unsigned short* Wih_lo = (unsigned short*)alloc(384 * 128 * 2);
  unsigned short* Whh_hi = (unsigned short*)alloc(384 * 128 * 2);
  unsigned short* Whh_lo = (unsigned short*)alloc(384 * 128 * 2);

  // init + CSR + weight prep (once per launch)
  k_init<<<(Np * DD + 255) / 256, 256, 0, stream>>>(annotation, hP_hi[0], hP_lo[0], N, Np);
  hipMemsetAsync(deg, 0, (size_t)N * 4, stream);
  hipMemsetAsync(cursor, 0, (size_t)N * 4, stream);
  hipMemsetAsync(deg4, 0, (size_t)N * 16, stream);
  hipMemsetAsync(startg, 0x7f, (size_t)B * 4, stream);
  hipMemsetAsync(endg, 0, (size_t)B * 4, stream);
  k_deg<<<(E + 255) / 256, 256, 0, stream>>>(dst, deg, E);
  k_deg4<<<(E + 255) / 256, 256, 0, stream>>>(dst, et, deg4, E);
  k_scan<<<1, 1024, 0, stream>>>(deg, base, N);
  k_place<<<(E + 255) / 256, 256, 0, stream>>>(src, dst, et, base, cursor, csrc, cet, E);
  k_bounds<<<(N + 255) / 256, 256, 0, stream>>>(n2g, startg, endg, N);
  k_repack_wlin<<<(128 * 512 + 255) / 256, 256, 0, stream>>>(W_lin, WlT_hi, WlT_lo);
  k_splitw<<<(384 * 128 + 255) / 256, 256, 0, stream>>>(W_ih, Wih_hi, Wih_lo, 384 * 128);
  k_splitw<<<(384 * 128 + 255) / 256, 256, 0, stream>>>(W_hh, Whh_hi, Whh_lo, 384 * 128);

  int cur = 0;
  for (int s = 0; s < NSTEPS; ++s) {
    int nxt = cur ^ 1;
    for (int nbase = 0; nbase < N; nbase += CHUNK) {
      int cc = min(CHUNK, N - nbase);
      int cgrid = (cc + 63) / 64;
      k_aggh<<<(cc + 1) / 2, 256, 0, stream>>>(
          hP_hi[cur], hP_lo[cur], base, csrc, cet, A3hi, A3lo, nbase, cc);
      // a = A3 @ WlinT^T + deg-bias  -> split planes
      k_gemm<1><<<dim3(cgrid, 2), 256, 0, stream>>>(A3hi, A3lo, 512, 512,
          WlT_hi, WlT_lo, b_lin, deg4 + (size_t)nbase * 4,
          (float*)nullptr, 0, a_hi, a_lo, cc);
      // gi = a @ W_ih^T + b_ih
      k_gemm<0><<<dim3(cgrid, 6), 256, 0, stream>>>(a_hi, a_lo, 128, 128,
          Wih_hi, Wih_lo, b_ih, (const int*)nullptr, gi, 384,
          (unsigned short*)nullptr, (unsigned short*)nullptr, cc);
      // gh = h @ W_hh^T + b_hh
      k_gemm<0><<<dim3(cgrid, 6), 256, 0, stream>>>(
          hP_hi[cur] + (size_t)nbase * DD, hP_lo[cur] + (size_t)nbase * DD, 128, 128,
          Whh_hi, Whh_lo, b_hh, (const int*)nullptr, gh, 384,
          (unsigned short*)nullptr, (unsigned short*)nullptr, cc);
      k_gruel<<<(cc * DD + 255) / 256, 256, 0, stream>>>(
          gi, gh, hP_hi[cur], hP_lo[cur], hP_hi[nxt], hP_lo[nxt], nbase, cc);
    }
    cur ^= 1;
  }

  k_gate<<<(N * 64 + 255) / 256, 256, 0, stream>>>(
      hP_hi[cur], hP_lo[cur], annotation, gate_w, gate_b, gate, N);
  k_pool<<<B, 256, 0, stream>>>(gate, ex, hP_hi[cur], hP_lo[cur], annotation,
      startg, endg, readout, N);
  k_logits<<<1, 64, 0, stream>>>(readout, out_w, out_b, labels, (float*)d_out, B);
}

// Round 5
// 2902.948 us; speedup vs baseline: 6.3092x; 1.4116x over previous
//
#include <hip/hip_runtime.h>
#include <math.h>

#define DD 128      // hidden dim
#define ANND 64     // annotation dim
#define NSTEPS 5
#define NTYPES 4
#define NCLS 10
#define CHUNK 12544 // nodes per pipeline chunk (multiple of 64)

typedef __attribute__((ext_vector_type(8))) short short8v;  // 8 bf16
typedef __attribute__((ext_vector_type(4))) float f32x4;

// split fp32 into hi+lo bf16 (RNE both)
__device__ __forceinline__ void split2(float x, unsigned short& hi, unsigned short& lo) {
  unsigned u = __float_as_uint(x);
  unsigned hb = (u + 0x7FFFu + ((u >> 16) & 1u)) >> 16;
  hi = (unsigned short)hb;
  float r = x - __uint_as_float(hb << 16);
  unsigned v = __float_as_uint(r);
  lo = (unsigned short)((v + 0x7FFFu + ((v >> 16) & 1u)) >> 16);
}

__device__ __forceinline__ float bf2f(unsigned short u) {
  return __uint_as_float(((unsigned)u) << 16);
}
__device__ __forceinline__ float rec2(const unsigned short* hi, const unsigned short* lo, size_t i) {
  return bf2f(hi[i]) + bf2f(lo[i]);
}

// h = [ann | 0] as split planes; zero-fill padded rows [n, npad)
__global__ void k_init(const float* __restrict__ ann,
    unsigned short* __restrict__ hhi, unsigned short* __restrict__ hlo, int n, int npad) {
  int idx = blockIdx.x * blockDim.x + threadIdx.x;
  if (idx >= npad * DD) return;
  int node = idx >> 7, d = idx & 127;
  float v = (node < n && d < ANND) ? ann[node * ANND + d] : 0.0f;
  unsigned short hi, lo; split2(v, hi, lo);
  hhi[idx] = hi; hlo[idx] = lo;
}

// ---------- CSR build (by dst), once per launch ----------
__global__ void k_deg(const int* __restrict__ dst, int* __restrict__ deg, int e) {
  int i = blockIdx.x * blockDim.x + threadIdx.x;
  if (i < e) atomicAdd(&deg[dst[i]], 1);
}

__global__ void k_deg4(const int* __restrict__ dst, const int* __restrict__ et,
    int* __restrict__ deg4, int e) {
  int i = blockIdx.x * blockDim.x + threadIdx.x;
  if (i < e) atomicAdd(&deg4[dst[i] * 4 + et[i]], 1);
}

__global__ __launch_bounds__(1024) void k_scan(const int* __restrict__ deg,
    int* __restrict__ base, int n) {
  __shared__ int part[1024];
  int t = threadIdx.x;
  int chunk = (n + 1023) >> 10;
  int s = t * chunk, e = min(n, s + chunk);
  int sum = 0;
  for (int i = s; i < e; ++i) sum += deg[i];
  part[t] = sum;
  __syncthreads();
  int own = sum;
  for (int off = 1; off < 1024; off <<= 1) {
    int v = (t >= off) ? part[t - off] : 0;
    __syncthreads();
    part[t] += v;
    __syncthreads();
  }
  int run = part[t] - own;
  for (int i = s; i < e; ++i) { base[i] = run; run += deg[i]; }
  if (s < n && e == n) base[n] = run;
}

__global__ void k_place(const int* __restrict__ src, const int* __restrict__ dst,
    const int* __restrict__ et, const int* __restrict__ base, int* __restrict__ cursor,
    int* __restrict__ csrc, int* __restrict__ cet, int e) {
  int i = blockIdx.x * blockDim.x + threadIdx.x;
  if (i >= e) return;
  int d = dst[i];
  int pos = base[d] + atomicAdd(&cursor[d], 1);
  csrc[pos] = src[i];
  cet[pos]  = et[i];
}

// ---------- per-type neighbor sums for one chunk ----------
__global__ void k_aggh(const unsigned short* __restrict__ hhi,
    const unsigned short* __restrict__ hlo, const int* __restrict__ base,
    const int* __restrict__ csrc, const int* __restrict__ cet,
    unsigned short* __restrict__ A3hi, unsigned short* __restrict__ A3lo,
    int nbase, int cc) {
  int local = blockIdx.x * 2 + (threadIdx.x >> 7);
  int c = threadIdx.x & 127;
  if (local >= cc) return;
  int node = nbase + local;
  int s = base[node], e = base[node + 1];
  float s0 = 0.f, s1 = 0.f, s2 = 0.f, s3 = 0.f;
  for (int i = s; i < e; ++i) {
    float v = rec2(hhi, hlo, (size_t)csrc[i] * DD + c);
    int t = cet[i];                       // wave-uniform branch
    if (t == 0) s0 += v; else if (t == 1) s1 += v;
    else if (t == 2) s2 += v; else s3 += v;
  }
  size_t b = (size_t)local * 512 + c;
  unsigned short hi, lo;
  split2(s0, hi, lo); A3hi[b]       = hi; A3lo[b]       = lo;
  split2(s1, hi, lo); A3hi[b + 128] = hi; A3lo[b + 128] = lo;
  split2(s2, hi, lo); A3hi[b + 256] = hi; A3lo[b + 256] = lo;
  split2(s3, hi, lo); A3hi[b + 384] = hi; A3lo[b + 384] = lo;
}

// ---------- MFMA GEMM (a-computation): C = A3 @ WlT^T + deg-bias, split store ----------
__global__ __launch_bounds__(256) void k_gemm_a(
    const unsigned short* __restrict__ Ahi, const unsigned short* __restrict__ Alo,
    const unsigned short* __restrict__ Whi, const unsigned short* __restrict__ Wlo,
    const float* __restrict__ bias, const int* __restrict__ deg4,
    unsigned short* __restrict__ Chi, unsigned short* __restrict__ Clo, int n) {
  int wid = threadIdx.x >> 6, lane = threadIdx.x & 63;
  int rowbase = blockIdx.x * 64 + (wid >> 1) * 32;
  int colbase = blockIdx.y * 64 + (wid & 1) * 32;
  int lr = lane & 15, lk = lane >> 4;
  f32x4 acc[2][2];
  #pragma unroll
  for (int nn = 0; nn < 2; ++nn)
    #pragma unroll
    for (int mm = 0; mm < 2; ++mm) acc[mm][nn] = (f32x4){0.f, 0.f, 0.f, 0.f};
  for (int k0 = 0; k0 < 512; k0 += 32) {
    int koff = k0 + lk * 8;
    short8v ah[2], al[2], bh[2], bl[2];
    #pragma unroll
    for (int mm = 0; mm < 2; ++mm) {
      size_t off = (size_t)(rowbase + mm * 16 + lr) * 512 + koff;
      ah[mm] = *(const short8v*)(Ahi + off);
      al[mm] = *(const short8v*)(Alo + off);
    }
    #pragma unroll
    for (int nn = 0; nn < 2; ++nn) {
      size_t off = (size_t)(colbase + nn * 16 + lr) * 512 + koff;
      bh[nn] = *(const short8v*)(Whi + off);
      bl[nn] = *(const short8v*)(Wlo + off);
    }
    #pragma unroll
    for (int mm = 0; mm < 2; ++mm)
      #pragma unroll
      for (int nn = 0; nn < 2; ++nn) {
        acc[mm][nn] = __builtin_amdgcn_mfma_f32_16x16x32_bf16(ah[mm], bh[nn], acc[mm][nn], 0, 0, 0);
        acc[mm][nn] = __builtin_amdgcn_mfma_f32_16x16x32_bf16(ah[mm], bl[nn], acc[mm][nn], 0, 0, 0);
        acc[mm][nn] = __builtin_amdgcn_mfma_f32_16x16x32_bf16(al[mm], bh[nn], acc[mm][nn], 0, 0, 0);
      }
  }
  #pragma unroll
  for (int mm = 0; mm < 2; ++mm) {
    #pragma unroll
    for (int j = 0; j < 4; ++j) {
      int row = rowbase + mm * 16 + lk * 4 + j;
      if (row < n) {
        int4 dg = *(const int4*)(deg4 + (size_t)row * 4);
        #pragma unroll
        for (int nn = 0; nn < 2; ++nn) {
          int col = colbase + nn * 16 + lr;
          float v = acc[mm][nn][j] + dg.x * bias[col] + dg.y * bias[128 + col]
                  + dg.z * bias[256 + col] + dg.w * bias[384 + col];
          unsigned short hi, lo; split2(v, hi, lo);
          Chi[(size_t)row * DD + col] = hi;
          Clo[(size_t)row * DD + col] = lo;
        }
      }
    }
  }
}

// ---------- fused GRU: gi+gh GEMMs + gate math, writes h' split planes ----------
// block: 64 nodes x 64 d-cols; wave = 32 rows x 32 cols.
// sr = a@Wr_ih + h@Wr_hh + br_i + br_h ; sz likewise ; gn = a@Wn_ih + bn_i ; hn = h@Wn_hh + bn_h
__global__ __launch_bounds__(256) void k_grufuse(
    const unsigned short* __restrict__ Ahi, const unsigned short* __restrict__ Alo,
    const unsigned short* __restrict__ Hhi, const unsigned short* __restrict__ Hlo,
    const unsigned short* __restrict__ WihH, const unsigned short* __restrict__ WihL,
    const unsigned short* __restrict__ WhhH, const unsigned short* __restrict__ WhhL,
    const float* __restrict__ bih, const float* __restrict__ bhh,
    unsigned short* __restrict__ Ohi, unsigned short* __restrict__ Olo,
    int nbase, int cc) {
  int wid = threadIdx.x >> 6, lane = threadIdx.x & 63;
  int rb = blockIdx.x * 64 + (wid & 1) * 32;    // chunk-local row base
  int cb = blockIdx.y * 64 + (wid >> 1) * 32;   // d col base
  int lr = lane & 15, lk = lane >> 4;
  f32x4 sr[2][2], sz[2][2], gn[2][2], hn[2][2];
  #pragma unroll
  for (int nn = 0; nn < 2; ++nn) {
    int col = cb + nn * 16 + lr;
    float br = bih[col] + bhh[col];
    float bz = bih[DD + col] + bhh[DD + col];
    float bi = bih[2 * DD + col];
    float bh = bhh[2 * DD + col];
    #pragma unroll
    for (int mm = 0; mm < 2; ++mm) {
      sr[mm][nn] = (f32x4){br, br, br, br};
      sz[mm][nn] = (f32x4){bz, bz, bz, bz};
      gn[mm][nn] = (f32x4){bi, bi, bi, bi};
      hn[mm][nn] = (f32x4){bh, bh, bh, bh};
    }
  }
  for (int k0 = 0; k0 < DD; k0 += 32) {
    int koff = k0 + lk * 8;
    short8v ah[2], al[2], hh_[2], hl_[2];
    #pragma unroll
    for (int mm = 0; mm < 2; ++mm) {
      size_t ao = (size_t)(rb + mm * 16 + lr) * DD + koff;
      ah[mm] = *(const short8v*)(Ahi + ao);
      al[mm] = *(const short8v*)(Alo + ao);
      size_t ho = (size_t)(nbase + rb + mm * 16 + lr) * DD + koff;
      hh_[mm] = *(const short8v*)(Hhi + ho);
      hl_[mm] = *(const short8v*)(Hlo + ho);
    }
    #pragma unroll
    for (int nn = 0; nn < 2; ++nn) {
      int c16 = cb + nn * 16 + lr;
      {  // r gate
        short8v wiH = *(const short8v*)(WihH + (size_t)c16 * DD + koff);
        short8v wiL = *(const short8v*)(WihL + (size_t)c16 * DD + koff);
        short8v whH = *(const short8v*)(WhhH + (size_t)c16 * DD + koff);
        short8v whL = *(const short8v*)(WhhL + (size_t)c16 * DD + koff);
        #pragma unroll
        for (int mm = 0; mm < 2; ++mm) {
          sr[mm][nn] = __builtin_amdgcn_mfma_f32_16x16x32_bf16(ah[mm], wiH, sr[mm][nn], 0, 0, 0);
          sr[mm][nn] = __builtin_amdgcn_mfma_f32_16x16x32_bf16(ah[mm], wiL, sr[mm][nn], 0, 0, 0);
          sr[mm][nn] = __builtin_amdgcn_mfma_f32_16x16x32_bf16(al[mm], wiH, sr[mm][nn], 0, 0, 0);
          sr[mm][nn] = __builtin_amdgcn_mfma_f32_16x16x32_bf16(hh_[mm], whH, sr[mm][nn], 0, 0, 0);
          sr[mm][nn] = __builtin_amdgcn_mfma_f32_16x16x32_bf16(hh_[mm], whL, sr[mm][nn], 0, 0, 0);
          sr[mm][nn] = __builtin_amdgcn_mfma_f32_16x16x32_bf16(hl_[mm], whH, sr[mm][nn], 0, 0, 0);
        }
      }
      {  // z gate
        int rz = DD + c16;
        short8v wiH = *(const short8v*)(WihH + (size_t)rz * DD + koff);
        short8v wiL = *(const short8v*)(WihL + (size_t)rz * DD + koff);
        short8v whH = *(const short8v*)(WhhH + (size_t)rz * DD + koff);
        short8v whL = *(const short8v*)(WhhL + (size_t)rz * DD + koff);
        #pragma unroll
        for (int mm = 0; mm < 2; ++mm) {
          sz[mm][nn] = __builtin_amdgcn_mfma_f32_16x16x32_bf16(ah[mm], wiH, sz[mm][nn], 0, 0, 0);
          sz[mm][nn] = __builtin_amdgcn_mfma_f32_16x16x32_bf16(ah[mm], wiL, sz[mm][nn], 0, 0, 0);
          sz[mm][nn] = __builtin_amdgcn_mfma_f32_16x16x32_bf16(al[mm], wiH, sz[mm][nn], 0, 0, 0);
          sz[mm][nn] = __builtin_amdgcn_mfma_f32_16x16x32_bf16(hh_[mm], whH, sz[mm][nn], 0, 0, 0);
          sz[mm][nn] = __builtin_amdgcn_mfma_f32_16x16x32_bf16(hh_[mm], whL, sz[mm][nn], 0, 0, 0);
          sz[mm][nn] = __builtin_amdgcn_mfma_f32_16x16x32_bf16(hl_[mm], whH, sz[mm][nn], 0, 0, 0);
        }
      }
      {  // n gate
        int rn = 2 * DD + c16;
        short8v wiH = *(const short8v*)(WihH + (size_t)rn * DD + koff);
        short8v wiL = *(const short8v*)(WihL + (size_t)rn * DD + koff);
        short8v whH = *(const short8v*)(WhhH + (size_t)rn * DD + koff);
        short8v whL = *(const short8v*)(WhhL + (size_t)rn * DD + koff);
        #pragma unroll
        for (int mm = 0; mm < 2; ++mm) {
          gn[mm][nn] = __builtin_amdgcn_mfma_f32_16x16x32_bf16(ah[mm], wiH, gn[mm][nn], 0, 0, 0);
          gn[mm][nn] = __builtin_amdgcn_mfma_f32_16x16x32_bf16(ah[mm], wiL, gn[mm][nn], 0, 0, 0);
          gn[mm][nn] = __builtin_amdgcn_mfma_f32_16x16x32_bf16(al[mm], wiH, gn[mm][nn], 0, 0, 0);
          hn[mm][nn] = __builtin_amdgcn_mfma_f32_16x16x32_bf16(hh_[mm], whH, hn[mm][nn], 0, 0, 0);
          hn[mm][nn] = __builtin_amdgcn_mfma_f32_16x16x32_bf16(hh_[mm], whL, hn[mm][nn], 0, 0, 0);
          hn[mm][nn] = __builtin_amdgcn_mfma_f32_16x16x32_bf16(hl_[mm], whH, hn[mm][nn], 0, 0, 0);
        }
      }
    }
  }
  #pragma unroll
  for (int mm = 0; mm < 2; ++mm) {
    #pragma unroll
    for (int j = 0; j < 4; ++j) {
      int row = rb + mm * 16 + lk * 4 + j;
      if (row < cc) {
        #pragma unroll
        for (int nn = 0; nn < 2; ++nn) {
          int col = cb + nn * 16 + lr;
          float r = 1.f / (1.f + expf(-sr[mm][nn][j]));
          float z = 1.f / (1.f + expf(-sz[mm][nn][j]));
          float nt = tanhf(gn[mm][nn][j] + r * hn[mm][nn][j]);
          size_t gidx = (size_t)(nbase + row) * DD + col;
          float hv = (1.f - z) * nt + z * rec2(Hhi, Hlo, gidx);
          unsigned short uh, ul; split2(hv, uh, ul);
          Ohi[gidx] = uh; Olo[gidx] = ul;
        }
      }
    }
  }
}

// ---------- weight prep ----------
__global__ void k_repack_wlin(const float* __restrict__ W,
    unsigned short* __restrict__ hi_, unsigned short* __restrict__ lo_) {
  int idx = blockIdx.x * blockDim.x + threadIdx.x;
  if (idx >= 128 * 512) return;
  int o = idx >> 9, kd = idx & 511;
  int k = kd >> 7, d = kd & 127;
  float v = W[k * 16384 + o * 128 + d];
  unsigned short h, l; split2(v, h, l);
  hi_[idx] = h; lo_[idx] = l;
}

__global__ void k_splitw(const float* __restrict__ x,
    unsigned short* __restrict__ hi_, unsigned short* __restrict__ lo_, int n) {
  int i = blockIdx.x * blockDim.x + threadIdx.x;
  if (i >= n) return;
  unsigned short h, l; split2(x[i], h, l);
  hi_[i] = h; lo_[i] = l;
}

// ---------- readout ----------
__global__ void k_gate(const unsigned short* __restrict__ hhi,
    const unsigned short* __restrict__ hlo, const float* __restrict__ ann,
    const float* __restrict__ gw, const float* __restrict__ gb,
    float* __restrict__ gate, int n) {
  int gt = blockIdx.x * blockDim.x + threadIdx.x;
  int wv = gt >> 6;
  int lane = threadIdx.x & 63;
  if (wv >= n) return;
  float p = rec2(hhi, hlo, (size_t)wv * DD + lane) * gw[lane]
          + rec2(hhi, hlo, (size_t)wv * DD + 64 + lane) * gw[64 + lane]
          + ann[(size_t)wv * ANND + lane] * gw[128 + lane];
  for (int off = 32; off; off >>= 1) p += __shfl_down(p, off);
  if (lane == 0) gate[wv] = p + gb[0];
}

__global__ void k_bounds(const int* __restrict__ n2g, int* __restrict__ startg,
    int* __restrict__ endg, int n) {
  int i = blockIdx.x * blockDim.x + threadIdx.x;
  if (i >= n) return;
  int g = n2g[i];
  atomicMin(&startg[g], i);
  atomicMax(&endg[g], i + 1);
}

// segment softmax + attention readout; node-parallel, coalesced, deterministic
__global__ __launch_bounds__(256) void k_pool(const float* __restrict__ gate,
    const unsigned short* __restrict__ hhi, const unsigned short* __restrict__ hlo,
    const float* __restrict__ ann, const int* __restrict__ startg,
    const int* __restrict__ endg, float* __restrict__ readout) {
  __shared__ float red[256];
  __shared__ float alpha_s[1024];
  __shared__ float m_s, den_s;
  int g = blockIdx.x;
  int s = startg[g], e = endg[g];
  int tid = threadIdx.x;
  float m = -1e30f;
  for (int i = s + tid; i < e; i += 256) m = fmaxf(m, gate[i]);
  red[tid] = m; __syncthreads();
  for (int off = 128; off; off >>= 1) {
    if (tid < off) red[tid] = fmaxf(red[tid], red[tid + off]);
    __syncthreads();
  }
  if (tid == 0) m_s = red[0];
  __syncthreads();
  m = m_s;
  float sum = 0.f;
  for (int i = s + tid; i < e; i += 256) sum += expf(gate[i] - m);
  red[tid] = sum; __syncthreads();
  for (int off = 128; off; off >>= 1) {
    if (tid < off) red[tid] += red[tid + off];
    __syncthreads();
  }
  if (tid == 0) den_s = red[0];
  __syncthreads();
  float inv = (s < e) ? 1.f / den_s : 0.f;
  int nl2 = tid >> 7, d2 = tid & 127;
  int nl4 = tid >> 6, d4 = tid & 63;
  float accH = 0.f, accA = 0.f;
  for (int t0 = s; t0 < e; t0 += 1024) {
    int te = min(e, t0 + 1024);
    __syncthreads();
    for (int i = t0 + tid; i < te; i += 256)
      alpha_s[i - t0] = expf(gate[i] - m) * inv;
    __syncthreads();
    for (int i = t0 + nl2; i < te; i += 2)
      accH += alpha_s[i - t0] * rec2(hhi, hlo, (size_t)i * DD + d2);
    for (int i = t0 + nl4; i < te; i += 4)
      accA += alpha_s[i - t0] * ann[(size_t)i * ANND + d4];
  }
  __syncthreads();
  red[tid] = accH; __syncthreads();
  if (tid < 128) readout[g * (DD + ANND) + tid] = red[tid] + red[128 + tid];
  __syncthreads();
  red[tid] = accA; __syncthreads();
  if (tid < 64)
    readout[g * (DD + ANND) + DD + tid] =
        red[tid] + red[64 + tid] + red[128 + tid] + red[192 + tid];
}

__global__ void k_logits(const float* __restrict__ readout, const float* __restrict__ ow,
    const float* __restrict__ ob, const int* __restrict__ labels,
    float* __restrict__ out, int B) {
  __shared__ float lsum[64];
  int g = threadIdx.x;
  float loss_c = 0.f;
  if (g < B) {
    float lg[NCLS];
    float mx = -1e30f;
    int best = 0;
    for (int c = 0; c < NCLS; ++c) {
      float acc = ob[c];
      const float* r = readout + g * (DD + ANND);
      const float* w = ow + c * (DD + ANND);
      for (int d = 0; d < DD + ANND; ++d) acc += r[d] * w[d];
      lg[c] = acc;
      if (acc > mx) { mx = acc; best = c; }
    }
    float se = 0.f;
    for (int c = 0; c < NCLS; ++c) se += expf(lg[c] - mx);
    float lse = mx + logf(se);
    loss_c = -(lg[labels[g]] - lse);
    out[1 + g] = (float)best;
  }
  lsum[threadIdx.x] = loss_c;
  __syncthreads();
  for (int off = 32; off; off >>= 1) {
    if (threadIdx.x < off) lsum[threadIdx.x] += lsum[threadIdx.x + off];
    __syncthreads();
  }
  if (threadIdx.x == 0) out[0] = lsum[0] / (float)B;
}

extern "C" void kernel_launch(void* const* d_in, const int* in_sizes, int n_in,
                              void* d_out, int out_size, void* d_ws, size_t ws_size,
                              hipStream_t stream) {
  const float* annotation = (const float*)d_in[0];
  const int*   src        = (const int*)d_in[1];
  const int*   dst        = (const int*)d_in[2];
  const int*   et         = (const int*)d_in[3];
  const int*   n2g        = (const int*)d_in[4];
  const int*   labels     = (const int*)d_in[5];
  const float* W_lin      = (const float*)d_in[6];
  const float* b_lin      = (const float*)d_in[7];
  const float* W_ih       = (const float*)d_in[8];
  const float* W_hh       = (const float*)d_in[9];
  const float* b_ih       = (const float*)d_in[10];
  const float* b_hh       = (const float*)d_in[11];
  const float* gate_w     = (const float*)d_in[12];
  const float* gate_b     = (const float*)d_in[13];
  const float* out_w      = (const float*)d_in[14];
  const float* out_b      = (const float*)d_in[15];

  int N = in_sizes[0] / ANND;
  int E = in_sizes[1];
  int B = in_sizes[5];
  int Np = (N + 63) & ~63;

  char* wsP = (char*)d_ws;
  auto alloc = [&](size_t bytes) -> void* {
    void* p = (void*)wsP;
    wsP += (bytes + 255) & ~(size_t)255;
    return p;
  };
  // ping-pong h split planes (Np rows each)
  unsigned short* hP_hi[2], *hP_lo[2];
  hP_hi[0] = (unsigned short*)alloc((size_t)Np * DD * 2);
  hP_lo[0] = (unsigned short*)alloc((size_t)Np * DD * 2);
  hP_hi[1] = (unsigned short*)alloc((size_t)Np * DD * 2);
  hP_lo[1] = (unsigned short*)alloc((size_t)Np * DD * 2);
  // per-chunk buffers (reused)
  unsigned short* A3hi = (unsigned short*)alloc((size_t)CHUNK * 512 * 2);
  unsigned short* A3lo = (unsigned short*)alloc((size_t)CHUNK * 512 * 2);
  unsigned short* a_hi = (unsigned short*)alloc((size_t)CHUNK * DD * 2);
  unsigned short* a_lo = (unsigned short*)alloc((size_t)CHUNK * DD * 2);
  // small persistent
  float* gate = (float*)alloc((size_t)N * 4);
  float* readout = (float*)alloc((size_t)B * (DD + ANND) * 4);
  int* startg = (int*)alloc((size_t)B * 4);
  int* endg   = (int*)alloc((size_t)B * 4);
  int* deg    = (int*)alloc((size_t)N * 4);
  int* base   = (int*)alloc((size_t)(N + 1) * 4);
  int* cursor = (int*)alloc((size_t)N * 4);
  int* deg4   = (int*)alloc((size_t)N * 4 * 4);
  int* csrc   = (int*)alloc((size_t)E * 4);
  int* cet    = (int*)alloc((size_t)E * 4);
  unsigned short* WlT_hi = (unsigned short*)alloc(128 * 512 * 2);
  unsigned short* WlT_lo = (unsigned short*)alloc(128 * 512 * 2);
  unsigned short* Wih_hi = (unsigned short*)alloc(384 * 128 * 2);
  unsigned short* Wih_lo = (unsigned short*)alloc(384 * 128 * 2);
  unsigned short* Whh_hi = (unsigned short*)alloc(384 * 128 * 2);
  unsigned short* Whh_lo = (unsigned short*)alloc(384 * 128 * 2);

  // init + CSR + weight prep (once per launch)
  k_init<<<(Np * DD + 255) / 256, 256, 0, stream>>>(annotation, hP_hi[0], hP_lo[0], N, Np);
  hipMemsetAsync(deg, 0, (size_t)N * 4, stream);
  hipMemsetAsync(cursor, 0, (size_t)N * 4, stream);
  hipMemsetAsync(deg4, 0, (size_t)N * 16, stream);
  hipMemsetAsync(startg, 0x7f, (size_t)B * 4, stream);
  hipMemsetAsync(endg, 0, (size_t)B * 4, stream);
  k_deg<<<(E + 255) / 256, 256, 0, stream>>>(dst, deg, E);
  k_deg4<<<(E + 255) / 256, 256, 0, stream>>>(dst, et, deg4, E);
  k_scan<<<1, 1024, 0, stream>>>(deg, base, N);
  k_place<<<(E + 255) / 256, 256, 0, stream>>>(src, dst, et, base, cursor, csrc, cet, E);
  k_bounds<<<(N + 255) / 256, 256, 0, stream>>>(n2g, startg, endg, N);
  k_repack_wlin<<<(128 * 512 + 255) / 256, 256, 0, stream>>>(W_lin, WlT_hi, WlT_lo);
  k_splitw<<<(384 * 128 + 255) / 256, 256, 0, stream>>>(W_ih, Wih_hi, Wih_lo, 384 * 128);
  k_splitw<<<(384 * 128 + 255) / 256, 256, 0, stream>>>(W_hh, Whh_hi, Whh_lo, 384 * 128);

  int cur = 0;
  for (int s = 0; s < NSTEPS; ++s) {
    int nxt = cur ^ 1;
    for (int nbase = 0; nbase < N; nbase += CHUNK) {
      int cc = min(CHUNK, N - nbase);
      int cgrid = (cc + 63) / 64;
      k_aggh<<<(cc + 1) / 2, 256, 0, stream>>>(
          hP_hi[cur], hP_lo[cur], base, csrc, cet, A3hi, A3lo, nbase, cc);
      k_gemm_a<<<dim3(cgrid, 2), 256, 0, stream>>>(A3hi, A3lo,
          WlT_hi, WlT_lo, b_lin, deg4 + (size_t)nbase * 4, a_hi, a_lo, cc);
      k_grufuse<<<dim3(cgrid, 2), 256, 0, stream>>>(a_hi, a_lo,
          hP_hi[cur], hP_lo[cur], Wih_hi, Wih_lo, Whh_hi, Whh_lo,
          b_ih, b_hh, hP_hi[nxt], hP_lo[nxt], nbase, cc);
    }
    cur ^= 1;
  }

  k_gate<<<(N * 64 + 255) / 256, 256, 0, stream>>>(
      hP_hi[cur], hP_lo[cur], annotation, gate_w, gate_b, gate, N);
  k_pool<<<B, 256, 0, stream>>>(gate, hP_hi[cur], hP_lo[cur], annotation,
      startg, endg, readout);
  k_logits<<<1, 64, 0, stream>>>(readout, out_w, out_b, labels, (float*)d_out, B);
}

// Round 6
// 2228.991 us; speedup vs baseline: 8.2168x; 1.3024x over previous
//
#include <hip/hip_runtime.h>
#include <math.h>

#define DD 128      // hidden dim
#define ANND 64     // annotation dim
#define NSTEPS 5
#define NTYPES 4
#define NCLS 10

typedef __attribute__((ext_vector_type(8))) short short8v;  // 8 bf16
typedef __attribute__((ext_vector_type(4))) float f32x4;

// split fp32 into hi+lo bf16 (RNE both)
__device__ __forceinline__ void split2(float x, unsigned short& hi, unsigned short& lo) {
  unsigned u = __float_as_uint(x);
  unsigned hb = (u + 0x7FFFu + ((u >> 16) & 1u)) >> 16;
  hi = (unsigned short)hb;
  float r = x - __uint_as_float(hb << 16);
  unsigned v = __float_as_uint(r);
  lo = (unsigned short)((v + 0x7FFFu + ((v >> 16) & 1u)) >> 16);
}

__device__ __forceinline__ float bf2f(unsigned short u) {
  return __uint_as_float(((unsigned)u) << 16);
}
__device__ __forceinline__ float rec2(const unsigned short* hi, const unsigned short* lo, size_t i) {
  return bf2f(hi[i]) + bf2f(lo[i]);
}

// h = [ann | 0] as split planes; zero-fill padded rows [n, npad)
__global__ void k_init(const float* __restrict__ ann,
    unsigned short* __restrict__ hhi, unsigned short* __restrict__ hlo, int n, int npad) {
  int idx = blockIdx.x * blockDim.x + threadIdx.x;
  if (idx >= npad * DD) return;
  int node = idx >> 7, d = idx & 127;
  float v = (node < n && d < ANND) ? ann[node * ANND + d] : 0.0f;
  unsigned short hi, lo; split2(v, hi, lo);
  hhi[idx] = hi; hlo[idx] = lo;
}

// ---------- CSR build (by dst), once per launch ----------
__global__ void k_deg4(const int* __restrict__ dst, const int* __restrict__ et,
    int* __restrict__ deg4, int e) {
  int i = blockIdx.x * blockDim.x + threadIdx.x;
  if (i < e) atomicAdd(&deg4[dst[i] * 4 + et[i]], 1);
}

// exclusive scan over per-node total degree (sum of deg4) -> base[0..n]
__global__ __launch_bounds__(1024) void k_scan(const int* __restrict__ deg4,
    int* __restrict__ base, int n) {
  __shared__ int part[1024];
  int t = threadIdx.x;
  int chunk = (n + 1023) >> 10;
  int s = t * chunk, e = min(n, s + chunk);
  int sum = 0;
  for (int i = s; i < e; ++i) {
    const int4 d4 = *(const int4*)(deg4 + (size_t)i * 4);
    sum += d4.x + d4.y + d4.z + d4.w;
  }
  part[t] = sum;
  __syncthreads();
  int own = sum;
  for (int off = 1; off < 1024; off <<= 1) {
    int v = (t >= off) ? part[t - off] : 0;
    __syncthreads();
    part[t] += v;
    __syncthreads();
  }
  int run = part[t] - own;
  for (int i = s; i < e; ++i) {
    base[i] = run;
    const int4 d4 = *(const int4*)(deg4 + (size_t)i * 4);
    run += d4.x + d4.y + d4.z + d4.w;
  }
  if (s < n && e == n) base[n] = run;
}

__global__ void k_place(const int* __restrict__ src, const int* __restrict__ dst,
    const int* __restrict__ et, const int* __restrict__ base, int* __restrict__ cursor,
    int* __restrict__ csrc, int* __restrict__ cet, int e) {
  int i = blockIdx.x * blockDim.x + threadIdx.x;
  if (i >= e) return;
  int d = dst[i];
  int pos = base[d] + atomicAdd(&cursor[d], 1);
  csrc[pos] = src[i];
  cet[pos]  = et[i];
}

// ---------- per-type neighbor sums for one chunk ----------
__global__ void k_aggh(const unsigned short* __restrict__ hhi,
    const unsigned short* __restrict__ hlo, const int* __restrict__ base,
    const int* __restrict__ csrc, const int* __restrict__ cet,
    unsigned short* __restrict__ A3hi, unsigned short* __restrict__ A3lo,
    int nbase, int cc) {
  int local = blockIdx.x * 2 + (threadIdx.x >> 7);
  int c = threadIdx.x & 127;
  if (local >= cc) return;
  int node = nbase + local;
  int s = base[node], e = base[node + 1];
  float s0 = 0.f, s1 = 0.f, s2 = 0.f, s3 = 0.f;
  for (int i = s; i < e; ++i) {
    float v = rec2(hhi, hlo, (size_t)csrc[i] * DD + c);
    int t = cet[i];                       // wave-uniform branch
    if (t == 0) s0 += v; else if (t == 1) s1 += v;
    else if (t == 2) s2 += v; else s3 += v;
  }
  size_t b = (size_t)local * 512 + c;
  unsigned short hi, lo;
  split2(s0, hi, lo); A3hi[b]       = hi; A3lo[b]       = lo;
  split2(s1, hi, lo); A3hi[b + 128] = hi; A3lo[b + 128] = lo;
  split2(s2, hi, lo); A3hi[b + 256] = hi; A3lo[b + 256] = lo;
  split2(s3, hi, lo); A3hi[b + 384] = hi; A3lo[b + 384] = lo;
}

// ---------- MFMA GEMM (a-computation): C = A3 @ WlT^T + deg-bias, split store ----------
__global__ __launch_bounds__(256) void k_gemm_a(
    const unsigned short* __restrict__ Ahi, const unsigned short* __restrict__ Alo,
    const unsigned short* __restrict__ Whi, const unsigned short* __restrict__ Wlo,
    const float* __restrict__ bias, const int* __restrict__ deg4,
    unsigned short* __restrict__ Chi, unsigned short* __restrict__ Clo, int n) {
  int wid = threadIdx.x >> 6, lane = threadIdx.x & 63;
  int rowbase = blockIdx.x * 64 + (wid >> 1) * 32;
  int colbase = blockIdx.y * 64 + (wid & 1) * 32;
  int lr = lane & 15, lk = lane >> 4;
  f32x4 acc[2][2];
  #pragma unroll
  for (int nn = 0; nn < 2; ++nn)
    #pragma unroll
    for (int mm = 0; mm < 2; ++mm) acc[mm][nn] = (f32x4){0.f, 0.f, 0.f, 0.f};
  for (int k0 = 0; k0 < 512; k0 += 32) {
    int koff = k0 + lk * 8;
    short8v ah[2], al[2], bh[2], bl[2];
    #pragma unroll
    for (int mm = 0; mm < 2; ++mm) {
      size_t off = (size_t)(rowbase + mm * 16 + lr) * 512 + koff;
      ah[mm] = *(const short8v*)(Ahi + off);
      al[mm] = *(const short8v*)(Alo + off);
    }
    #pragma unroll
    for (int nn = 0; nn < 2; ++nn) {
      size_t off = (size_t)(colbase + nn * 16 + lr) * 512 + koff;
      bh[nn] = *(const short8v*)(Whi + off);
      bl[nn] = *(const short8v*)(Wlo + off);
    }
    #pragma unroll
    for (int mm = 0; mm < 2; ++mm)
      #pragma unroll
      for (int nn = 0; nn < 2; ++nn) {
        acc[mm][nn] = __builtin_amdgcn_mfma_f32_16x16x32_bf16(ah[mm], bh[nn], acc[mm][nn], 0, 0, 0);
        acc[mm][nn] = __builtin_amdgcn_mfma_f32_16x16x32_bf16(ah[mm], bl[nn], acc[mm][nn], 0, 0, 0);
        acc[mm][nn] = __builtin_amdgcn_mfma_f32_16x16x32_bf16(al[mm], bh[nn], acc[mm][nn], 0, 0, 0);
      }
  }
  #pragma unroll
  for (int mm = 0; mm < 2; ++mm) {
    #pragma unroll
    for (int j = 0; j < 4; ++j) {
      int row = rowbase + mm * 16 + lk * 4 + j;
      if (row < n) {
        int4 dg = *(const int4*)(deg4 + (size_t)row * 4);
        #pragma unroll
        for (int nn = 0; nn < 2; ++nn) {
          int col = colbase + nn * 16 + lr;
          float v = acc[mm][nn][j] + dg.x * bias[col] + dg.y * bias[128 + col]
                  + dg.z * bias[256 + col] + dg.w * bias[384 + col];
          unsigned short hi, lo; split2(v, hi, lo);
          Chi[(size_t)row * DD + col] = hi;
          Clo[(size_t)row * DD + col] = lo;
        }
      }
    }
  }
}

// ---------- fused GRU: gi+gh GEMMs + gate math, writes h' split planes ----------
__global__ __launch_bounds__(256) void k_grufuse(
    const unsigned short* __restrict__ Ahi, const unsigned short* __restrict__ Alo,
    const unsigned short* __restrict__ Hhi, const unsigned short* __restrict__ Hlo,
    const unsigned short* __restrict__ WihH, const unsigned short* __restrict__ WihL,
    const unsigned short* __restrict__ WhhH, const unsigned short* __restrict__ WhhL,
    const float* __restrict__ bih, const float* __restrict__ bhh,
    unsigned short* __restrict__ Ohi, unsigned short* __restrict__ Olo,
    int nbase, int cc) {
  int wid = threadIdx.x >> 6, lane = threadIdx.x & 63;
  int rb = blockIdx.x * 64 + (wid & 1) * 32;    // chunk-local row base
  int cb = blockIdx.y * 64 + (wid >> 1) * 32;   // d col base
  int lr = lane & 15, lk = lane >> 4;
  f32x4 sr[2][2], sz[2][2], gn[2][2], hn[2][2];
  #pragma unroll
  for (int nn = 0; nn < 2; ++nn) {
    int col = cb + nn * 16 + lr;
    float br = bih[col] + bhh[col];
    float bz = bih[DD + col] + bhh[DD + col];
    float bi = bih[2 * DD + col];
    float bh = bhh[2 * DD + col];
    #pragma unroll
    for (int mm = 0; mm < 2; ++mm) {
      sr[mm][nn] = (f32x4){br, br, br, br};
      sz[mm][nn] = (f32x4){bz, bz, bz, bz};
      gn[mm][nn] = (f32x4){bi, bi, bi, bi};
      hn[mm][nn] = (f32x4){bh, bh, bh, bh};
    }
  }
  for (int k0 = 0; k0 < DD; k0 += 32) {
    int koff = k0 + lk * 8;
    short8v ah[2], al[2], hh_[2], hl_[2];
    #pragma unroll
    for (int mm = 0; mm < 2; ++mm) {
      size_t ao = (size_t)(rb + mm * 16 + lr) * DD + koff;
      ah[mm] = *(const short8v*)(Ahi + ao);
      al[mm] = *(const short8v*)(Alo + ao);
      size_t ho = (size_t)(nbase + rb + mm * 16 + lr) * DD + koff;
      hh_[mm] = *(const short8v*)(Hhi + ho);
      hl_[mm] = *(const short8v*)(Hlo + ho);
    }
    #pragma unroll
    for (int nn = 0; nn < 2; ++nn) {
      int c16 = cb + nn * 16 + lr;
      {  // r gate
        short8v wiH = *(const short8v*)(WihH + (size_t)c16 * DD + koff);
        short8v wiL = *(const short8v*)(WihL + (size_t)c16 * DD + koff);
        short8v whH = *(const short8v*)(WhhH + (size_t)c16 * DD + koff);
        short8v whL = *(const short8v*)(WhhL + (size_t)c16 * DD + koff);
        #pragma unroll
        for (int mm = 0; mm < 2; ++mm) {
          sr[mm][nn] = __builtin_amdgcn_mfma_f32_16x16x32_bf16(ah[mm], wiH, sr[mm][nn], 0, 0, 0);
          sr[mm][nn] = __builtin_amdgcn_mfma_f32_16x16x32_bf16(ah[mm], wiL, sr[mm][nn], 0, 0, 0);
          sr[mm][nn] = __builtin_amdgcn_mfma_f32_16x16x32_bf16(al[mm], wiH, sr[mm][nn], 0, 0, 0);
          sr[mm][nn] = __builtin_amdgcn_mfma_f32_16x16x32_bf16(hh_[mm], whH, sr[mm][nn], 0, 0, 0);
          sr[mm][nn] = __builtin_amdgcn_mfma_f32_16x16x32_bf16(hh_[mm], whL, sr[mm][nn], 0, 0, 0);
          sr[mm][nn] = __builtin_amdgcn_mfma_f32_16x16x32_bf16(hl_[mm], whH, sr[mm][nn], 0, 0, 0);
        }
      }
      {  // z gate
        int rz = DD + c16;
        short8v wiH = *(const short8v*)(WihH + (size_t)rz * DD + koff);
        short8v wiL = *(const short8v*)(WihL + (size_t)rz * DD + koff);
        short8v whH = *(const short8v*)(WhhH + (size_t)rz * DD + koff);
        short8v whL = *(const short8v*)(WhhL + (size_t)rz * DD + koff);
        #pragma unroll
        for (int mm = 0; mm < 2; ++mm) {
          sz[mm][nn] = __builtin_amdgcn_mfma_f32_16x16x32_bf16(ah[mm], wiH, sz[mm][nn], 0, 0, 0);
          sz[mm][nn] = __builtin_amdgcn_mfma_f32_16x16x32_bf16(ah[mm], wiL, sz[mm][nn], 0, 0, 0);
          sz[mm][nn] = __builtin_amdgcn_mfma_f32_16x16x32_bf16(al[mm], wiH, sz[mm][nn], 0, 0, 0);
          sz[mm][nn] = __builtin_amdgcn_mfma_f32_16x16x32_bf16(hh_[mm], whH, sz[mm][nn], 0, 0, 0);
          sz[mm][nn] = __builtin_amdgcn_mfma_f32_16x16x32_bf16(hh_[mm], whL, sz[mm][nn], 0, 0, 0);
          sz[mm][nn] = __builtin_amdgcn_mfma_f32_16x16x32_bf16(hl_[mm], whH, sz[mm][nn], 0, 0, 0);
        }
      }
      {  // n gate
        int rn = 2 * DD + c16;
        short8v wiH = *(const short8v*)(WihH + (size_t)rn * DD + koff);
        short8v wiL = *(const short8v*)(WihL + (size_t)rn * DD + koff);
        short8v whH = *(const short8v*)(WhhH + (size_t)rn * DD + koff);
        short8v whL = *(const short8v*)(WhhL + (size_t)rn * DD + koff);
        #pragma unroll
        for (int mm = 0; mm < 2; ++mm) {
          gn[mm][nn] = __builtin_amdgcn_mfma_f32_16x16x32_bf16(ah[mm], wiH, gn[mm][nn], 0, 0, 0);
          gn[mm][nn] = __builtin_amdgcn_mfma_f32_16x16x32_bf16(ah[mm], wiL, gn[mm][nn], 0, 0, 0);
          gn[mm][nn] = __builtin_amdgcn_mfma_f32_16x16x32_bf16(al[mm], wiH, gn[mm][nn], 0, 0, 0);
          hn[mm][nn] = __builtin_amdgcn_mfma_f32_16x16x32_bf16(hh_[mm], whH, hn[mm][nn], 0, 0, 0);
          hn[mm][nn] = __builtin_amdgcn_mfma_f32_16x16x32_bf16(hh_[mm], whL, hn[mm][nn], 0, 0, 0);
          hn[mm][nn] = __builtin_amdgcn_mfma_f32_16x16x32_bf16(hl_[mm], whH, hn[mm][nn], 0, 0, 0);
        }
      }
    }
  }
  #pragma unroll
  for (int mm = 0; mm < 2; ++mm) {
    #pragma unroll
    for (int j = 0; j < 4; ++j) {
      int row = rb + mm * 16 + lk * 4 + j;
      if (row < cc) {
        #pragma unroll
        for (int nn = 0; nn < 2; ++nn) {
          int col = cb + nn * 16 + lr;
          float r = 1.f / (1.f + expf(-sr[mm][nn][j]));
          float z = 1.f / (1.f + expf(-sz[mm][nn][j]));
          float nt = tanhf(gn[mm][nn][j] + r * hn[mm][nn][j]);
          size_t gidx = (size_t)(nbase + row) * DD + col;
          float hv = (1.f - z) * nt + z * rec2(Hhi, Hlo, gidx);
          unsigned short uh, ul; split2(hv, uh, ul);
          Ohi[gidx] = uh; Olo[gidx] = ul;
        }
      }
    }
  }
}

// ---------- weight prep ----------
__global__ void k_repack_wlin(const float* __restrict__ W,
    unsigned short* __restrict__ hi_, unsigned short* __restrict__ lo_) {
  int idx = blockIdx.x * blockDim.x + threadIdx.x;
  if (idx >= 128 * 512) return;
  int o = idx >> 9, kd = idx & 511;
  int k = kd >> 7, d = kd & 127;
  float v = W[k * 16384 + o * 128 + d];
  unsigned short h, l; split2(v, h, l);
  hi_[idx] = h; lo_[idx] = l;
}

__global__ void k_splitw(const float* __restrict__ x,
    unsigned short* __restrict__ hi_, unsigned short* __restrict__ lo_, int n) {
  int i = blockIdx.x * blockDim.x + threadIdx.x;
  if (i >= n) return;
  unsigned short h, l; split2(x[i], h, l);
  hi_[i] = h; lo_[i] = l;
}

// ---------- readout ----------
__global__ void k_gate(const unsigned short* __restrict__ hhi,
    const unsigned short* __restrict__ hlo, const float* __restrict__ ann,
    const float* __restrict__ gw, const float* __restrict__ gb,
    float* __restrict__ gate, int n) {
  int gt = blockIdx.x * blockDim.x + threadIdx.x;
  int wv = gt >> 6;
  int lane = threadIdx.x & 63;
  if (wv >= n) return;
  float p = rec2(hhi, hlo, (size_t)wv * DD + lane) * gw[lane]
          + rec2(hhi, hlo, (size_t)wv * DD + 64 + lane) * gw[64 + lane]
          + ann[(size_t)wv * ANND + lane] * gw[128 + lane];
  for (int off = 32; off; off >>= 1) p += __shfl_down(p, off);
  if (lane == 0) gate[wv] = p + gb[0];
}

// sorted node2graph -> segment bounds via boundary detection (no atomics)
__global__ void k_bounds(const int* __restrict__ n2g, int* __restrict__ startg,
    int* __restrict__ endg, int n) {
  int i = blockIdx.x * blockDim.x + threadIdx.x;
  if (i >= n) return;
  int g = n2g[i];
  if (i == 0 || n2g[i - 1] != g) startg[g] = i;
  if (i == n - 1 || n2g[i + 1] != g) endg[g] = i + 1;
}

// segment softmax + attention readout; node-parallel, coalesced, deterministic
__global__ __launch_bounds__(256) void k_pool(const float* __restrict__ gate,
    const unsigned short* __restrict__ hhi, const unsigned short* __restrict__ hlo,
    const float* __restrict__ ann, const int* __restrict__ startg,
    const int* __restrict__ endg, float* __restrict__ readout) {
  __shared__ float red[256];
  __shared__ float alpha_s[1024];
  __shared__ float m_s, den_s;
  int g = blockIdx.x;
  int s = startg[g], e = endg[g];
  int tid = threadIdx.x;
  float m = -1e30f;
  for (int i = s + tid; i < e; i += 256) m = fmaxf(m, gate[i]);
  red[tid] = m; __syncthreads();
  for (int off = 128; off; off >>= 1) {
    if (tid < off) red[tid] = fmaxf(red[tid], red[tid + off]);
    __syncthreads();
  }
  if (tid == 0) m_s = red[0];
  __syncthreads();
  m = m_s;
  float sum = 0.f;
  for (int i = s + tid; i < e; i += 256) sum += expf(gate[i] - m);
  red[tid] = sum; __syncthreads();
  for (int off = 128; off; off >>= 1) {
    if (tid < off) red[tid] += red[tid + off];
    __syncthreads();
  }
  if (tid == 0) den_s = red[0];
  __syncthreads();
  float inv = (s < e) ? 1.f / den_s : 0.f;
  int nl2 = tid >> 7, d2 = tid & 127;
  int nl4 = tid >> 6, d4 = tid & 63;
  float accH = 0.f, accA = 0.f;
  for (int t0 = s; t0 < e; t0 += 1024) {
    int te = min(e, t0 + 1024);
    __syncthreads();
    for (int i = t0 + tid; i < te; i += 256)
      alpha_s[i - t0] = expf(gate[i] - m) * inv;
    __syncthreads();
    for (int i = t0 + nl2; i < te; i += 2)
      accH += alpha_s[i - t0] * rec2(hhi, hlo, (size_t)i * DD + d2);
    for (int i = t0 + nl4; i < te; i += 4)
      accA += alpha_s[i - t0] * ann[(size_t)i * ANND + d4];
  }
  __syncthreads();
  red[tid] = accH; __syncthreads();
  if (tid < 128) readout[g * (DD + ANND) + tid] = red[tid] + red[128 + tid];
  __syncthreads();
  red[tid] = accA; __syncthreads();
  if (tid < 64)
    readout[g * (DD + ANND) + DD + tid] =
        red[tid] + red[64 + tid] + red[128 + tid] + red[192 + tid];
}

__global__ void k_logits(const float* __restrict__ readout, const float* __restrict__ ow,
    const float* __restrict__ ob, const int* __restrict__ labels,
    float* __restrict__ out, int B) {
  __shared__ float lsum[64];
  int g = threadIdx.x;
  float loss_c = 0.f;
  if (g < B) {
    float lg[NCLS];
    float mx = -1e30f;
    int best = 0;
    for (int c = 0; c < NCLS; ++c) {
      float acc = ob[c];
      const float* r = readout + g * (DD + ANND);
      const float* w = ow + c * (DD + ANND);
      for (int d = 0; d < DD + ANND; ++d) acc += r[d] * w[d];
      lg[c] = acc;
      if (acc > mx) { mx = acc; best = c; }
    }
    float se = 0.f;
    for (int c = 0; c < NCLS; ++c) se += expf(lg[c] - mx);
    float lse = mx + logf(se);
    loss_c = -(lg[labels[g]] - lse);
    out[1 + g] = (float)best;
  }
  lsum[threadIdx.x] = loss_c;
  __syncthreads();
  for (int off = 32; off; off >>= 1) {
    if (threadIdx.x < off) lsum[threadIdx.x] += lsum[threadIdx.x + off];
    __syncthreads();
  }
  if (threadIdx.x == 0) out[0] = lsum[0] / (float)B;
}

extern "C" void kernel_launch(void* const* d_in, const int* in_sizes, int n_in,
                              void* d_out, int out_size, void* d_ws, size_t ws_size,
                              hipStream_t stream) {
  const float* annotation = (const float*)d_in[0];
  const int*   src        = (const int*)d_in[1];
  const int*   dst        = (const int*)d_in[2];
  const int*   et         = (const int*)d_in[3];
  const int*   n2g        = (const int*)d_in[4];
  const int*   labels     = (const int*)d_in[5];
  const float* W_lin      = (const float*)d_in[6];
  const float* b_lin      = (const float*)d_in[7];
  const float* W_ih       = (const float*)d_in[8];
  const float* W_hh       = (const float*)d_in[9];
  const float* b_ih       = (const float*)d_in[10];
  const float* b_hh       = (const float*)d_in[11];
  const float* gate_w     = (const float*)d_in[12];
  const float* gate_b     = (const float*)d_in[13];
  const float* out_w      = (const float*)d_in[14];
  const float* out_b      = (const float*)d_in[15];

  int N = in_sizes[0] / ANND;
  int E = in_sizes[1];
  int B = in_sizes[5];
  int Np = (N + 63) & ~63;

  // ---- workspace budget: fixed allocations, then largest chunk that fits ----
  auto rup = [](size_t b) { return (b + 255) & ~(size_t)255; };
  size_t fixed = 0;
  fixed += 4 * rup((size_t)Np * DD * 2);           // h ping-pong planes
  fixed += rup((size_t)N * 4);                     // gate
  fixed += rup((size_t)B * (DD + ANND) * 4);       // readout
  fixed += 2 * rup((size_t)B * 4);                 // startg, endg
  fixed += rup((size_t)(N + 1) * 4);               // base
  fixed += rup((size_t)N * 4);                     // cursor
  fixed += rup((size_t)N * 16);                    // deg4
  fixed += 2 * rup((size_t)E * 4);                 // csrc, cet
  fixed += 2 * rup(128 * 512 * 2) + 4 * rup(384 * 128 * 2);  // weights
  size_t slack = 1 << 20;
  size_t avail = (ws_size > fixed + slack) ? ws_size - fixed - slack : 0;
  // per-chunk bytes: A3 planes (512*2*2) + a planes (128*2*2) = 2560/node
  long long ch = (long long)(avail / 2560);
  int CH = (int)((ch / 64) * 64);
  if (CH < 64) CH = 64;             // last-resort floor (R5 proved 12544 fits 93MB+)
  if (CH > Np) CH = Np;

  char* wsP = (char*)d_ws;
  auto alloc = [&](size_t bytes) -> void* {
    void* p = (void*)wsP;
    wsP += (bytes + 255) & ~(size_t)255;
    return p;
  };
  unsigned short* hP_hi[2], *hP_lo[2];
  hP_hi[0] = (unsigned short*)alloc((size_t)Np * DD * 2);
  hP_lo[0] = (unsigned short*)alloc((size_t)Np * DD * 2);
  hP_hi[1] = (unsigned short*)alloc((size_t)Np * DD * 2);
  hP_lo[1] = (unsigned short*)alloc((size_t)Np * DD * 2);
  float* gate = (float*)alloc((size_t)N * 4);
  float* readout = (float*)alloc((size_t)B * (DD + ANND) * 4);
  int* startg = (int*)alloc((size_t)B * 4);
  int* endg   = (int*)alloc((size_t)B * 4);
  int* base   = (int*)alloc((size_t)(N + 1) * 4);
  int* cursor = (int*)alloc((size_t)N * 4);
  int* deg4   = (int*)alloc((size_t)N * 16);
  int* csrc   = (int*)alloc((size_t)E * 4);
  int* cet    = (int*)alloc((size_t)E * 4);
  unsigned short* WlT_hi = (unsigned short*)alloc(128 * 512 * 2);
  unsigned short* WlT_lo = (unsigned short*)alloc(128 * 512 * 2);
  unsigned short* Wih_hi = (unsigned short*)alloc(384 * 128 * 2);
  unsigned short* Wih_lo = (unsigned short*)alloc(384 * 128 * 2);
  unsigned short* Whh_hi = (unsigned short*)alloc(384 * 128 * 2);
  unsigned short* Whh_lo = (unsigned short*)alloc(384 * 128 * 2);
  // chunk buffers last
  unsigned short* A3hi = (unsigned short*)alloc((size_t)CH * 512 * 2);
  unsigned short* A3lo = (unsigned short*)alloc((size_t)CH * 512 * 2);
  unsigned short* a_hi = (unsigned short*)alloc((size_t)CH * DD * 2);
  unsigned short* a_lo = (unsigned short*)alloc((size_t)CH * DD * 2);

  // init + CSR + weight prep (once per launch)
  k_init<<<(Np * DD + 255) / 256, 256, 0, stream>>>(annotation, hP_hi[0], hP_lo[0], N, Np);
  hipMemsetAsync(cursor, 0, (size_t)N * 4, stream);
  hipMemsetAsync(deg4, 0, (size_t)N * 16, stream);
  hipMemsetAsync(startg, 0x7f, (size_t)B * 4, stream);
  hipMemsetAsync(endg, 0, (size_t)B * 4, stream);
  k_deg4<<<(E + 255) / 256, 256, 0, stream>>>(dst, et, deg4, E);
  k_scan<<<1, 1024, 0, stream>>>(deg4, base, N);
  k_place<<<(E + 255) / 256, 256, 0, stream>>>(src, dst, et, base, cursor, csrc, cet, E);
  k_bounds<<<(N + 255) / 256, 256, 0, stream>>>(n2g, startg, endg, N);
  k_repack_wlin<<<(128 * 512 + 255) / 256, 256, 0, stream>>>(W_lin, WlT_hi, WlT_lo);
  k_splitw<<<(384 * 128 + 255) / 256, 256, 0, stream>>>(W_ih, Wih_hi, Wih_lo, 384 * 128);
  k_splitw<<<(384 * 128 + 255) / 256, 256, 0, stream>>>(W_hh, Whh_hi, Whh_lo, 384 * 128);

  int cur = 0;
  for (int s = 0; s < NSTEPS; ++s) {
    int nxt = cur ^ 1;
    for (int nbase = 0; nbase < N; nbase += CH) {
      int cc = min(CH, N - nbase);
      int cgrid = (cc + 63) / 64;
      k_aggh<<<(cc + 1) / 2, 256, 0, stream>>>(
          hP_hi[cur], hP_lo[cur], base, csrc, cet, A3hi, A3lo, nbase, cc);
      k_gemm_a<<<dim3(cgrid, 2), 256, 0, stream>>>(A3hi, A3lo,
          WlT_hi, WlT_lo, b_lin, deg4 + (size_t)nbase * 4, a_hi, a_lo, cc);
      k_grufuse<<<dim3(cgrid, 2), 256, 0, stream>>>(a_hi, a_lo,
          hP_hi[cur], hP_lo[cur], Wih_hi, Wih_lo, Whh_hi, Whh_lo,
          b_ih, b_hh, hP_hi[nxt], hP_lo[nxt], nbase, cc);
    }
    cur ^= 1;
  }

  k_gate<<<(N * 64 + 255) / 256, 256, 0, stream>>>(
      hP_hi[cur], hP_lo[cur], annotation, gate_w, gate_b, gate, N);
  k_pool<<<B, 256, 0, stream>>>(gate, hP_hi[cur], hP_lo[cur], annotation,
      startg, endg, readout);
  k_logits<<<1, 64, 0, stream>>>(readout, out_w, out_b, labels, (float*)d_out, B);
}

// Round 7
// 1699.735 us; speedup vs baseline: 10.7753x; 1.3114x over previous
//
#include <hip/hip_runtime.h>
#include <math.h>

#define DD 128      // hidden dim
#define ANND 64     // annotation dim
#define NSTEPS 5
#define NTYPES 4
#define NCLS 10

typedef __attribute__((ext_vector_type(8))) short short8v;  // 8 bf16
typedef __attribute__((ext_vector_type(4))) float f32x4;

// split fp32 into hi+lo bf16 (RNE both)
__device__ __forceinline__ void split2(float x, unsigned short& hi, unsigned short& lo) {
  unsigned u = __float_as_uint(x);
  unsigned hb = (u + 0x7FFFu + ((u >> 16) & 1u)) >> 16;
  hi = (unsigned short)hb;
  float r = x - __uint_as_float(hb << 16);
  unsigned v = __float_as_uint(r);
  lo = (unsigned short)((v + 0x7FFFu + ((v >> 16) & 1u)) >> 16);
}

__device__ __forceinline__ float bf2f(unsigned short u) {
  return __uint_as_float(((unsigned)u) << 16);
}
__device__ __forceinline__ float rec2(const unsigned short* hi, const unsigned short* lo, size_t i) {
  return bf2f(hi[i]) + bf2f(lo[i]);
}
__device__ __forceinline__ float lo16f(unsigned u) { return __uint_as_float(u << 16); }
__device__ __forceinline__ float hi16f(unsigned u) { return __uint_as_float(u & 0xffff0000u); }

// h = [ann | 0] as split planes; zero-fill padded rows [n, npad)
__global__ void k_init(const float* __restrict__ ann,
    unsigned short* __restrict__ hhi, unsigned short* __restrict__ hlo, int n, int npad) {
  int idx = blockIdx.x * blockDim.x + threadIdx.x;
  if (idx >= npad * DD) return;
  int node = idx >> 7, d = idx & 127;
  float v = (node < n && d < ANND) ? ann[node * ANND + d] : 0.0f;
  unsigned short hi, lo; split2(v, hi, lo);
  hhi[idx] = hi; hlo[idx] = lo;
}

// ---------- CSR build (by dst), once per launch ----------
__global__ void k_deg4(const int* __restrict__ dst, const int* __restrict__ et,
    int* __restrict__ deg4, int e) {
  int i = blockIdx.x * blockDim.x + threadIdx.x;
  if (i < e) atomicAdd(&deg4[dst[i] * 4 + et[i]], 1);
}

// exclusive scan over per-node total degree (sum of deg4) -> base[0..n]
__global__ __launch_bounds__(1024) void k_scan(const int* __restrict__ deg4,
    int* __restrict__ base, int n) {
  __shared__ int part[1024];
  int t = threadIdx.x;
  int chunk = (n + 1023) >> 10;
  int s = t * chunk, e = min(n, s + chunk);
  int sum = 0;
  for (int i = s; i < e; ++i) {
    const int4 d4 = *(const int4*)(deg4 + (size_t)i * 4);
    sum += d4.x + d4.y + d4.z + d4.w;
  }
  part[t] = sum;
  __syncthreads();
  int own = sum;
  for (int off = 1; off < 1024; off <<= 1) {
    int v = (t >= off) ? part[t - off] : 0;
    __syncthreads();
    part[t] += v;
    __syncthreads();
  }
  int run = part[t] - own;
  for (int i = s; i < e; ++i) {
    base[i] = run;
    const int4 d4 = *(const int4*)(deg4 + (size_t)i * 4);
    run += d4.x + d4.y + d4.z + d4.w;
  }
  if (s < n && e == n) base[n] = run;
}

// pack (et<<18)|src into one CSR payload array
__global__ void k_place(const int* __restrict__ src, const int* __restrict__ dst,
    const int* __restrict__ et, const int* __restrict__ base, int* __restrict__ cursor,
    int* __restrict__ cpack, int e) {
  int i = blockIdx.x * blockDim.x + threadIdx.x;
  if (i >= e) return;
  int d = dst[i];
  int pos = base[d] + atomicAdd(&cursor[d], 1);
  cpack[pos] = src[i] | (et[i] << 18);
}

// ---------- per-type neighbor sums: one WAVE per node, shfl-broadcast indices ----------
__global__ void k_aggh(const unsigned* __restrict__ hhiU, const unsigned* __restrict__ hloU,
    const int* __restrict__ base, const int* __restrict__ cpack,
    unsigned* __restrict__ A3hiU, unsigned* __restrict__ A3loU, int nbase, int cc) {
  int w = threadIdx.x >> 6;          // wave in block: 0..3
  int lane = threadIdx.x & 63;       // c-pair index (covers c=2*lane, 2*lane+1)
  int local = blockIdx.x * 4 + w;
  if (local >= cc) return;
  int node = nbase + local;
  int s = base[node], e = base[node + 1];
  float a0x = 0.f, a0y = 0.f, a1x = 0.f, a1y = 0.f;
  float a2x = 0.f, a2y = 0.f, a3x = 0.f, a3y = 0.f;
  for (int t0 = s; t0 < e; t0 += 64) {
    int cnt = min(64, e - t0);
    int mypk = (t0 + lane < e) ? cpack[t0 + lane] : 0;
    int i = 0;
    for (; i + 4 <= cnt; i += 4) {
      int pk0 = __shfl(mypk, i), pk1 = __shfl(mypk, i + 1);
      int pk2 = __shfl(mypk, i + 2), pk3 = __shfl(mypk, i + 3);
      unsigned uh0 = hhiU[(size_t)(pk0 & 0x3ffff) * 64 + lane];
      unsigned ul0 = hloU[(size_t)(pk0 & 0x3ffff) * 64 + lane];
      unsigned uh1 = hhiU[(size_t)(pk1 & 0x3ffff) * 64 + lane];
      unsigned ul1 = hloU[(size_t)(pk1 & 0x3ffff) * 64 + lane];
      unsigned uh2 = hhiU[(size_t)(pk2 & 0x3ffff) * 64 + lane];
      unsigned ul2 = hloU[(size_t)(pk2 & 0x3ffff) * 64 + lane];
      unsigned uh3 = hhiU[(size_t)(pk3 & 0x3ffff) * 64 + lane];
      unsigned ul3 = hloU[(size_t)(pk3 & 0x3ffff) * 64 + lane];
      float v0x = lo16f(uh0) + lo16f(ul0), v0y = hi16f(uh0) + hi16f(ul0);
      float v1x = lo16f(uh1) + lo16f(ul1), v1y = hi16f(uh1) + hi16f(ul1);
      float v2x = lo16f(uh2) + lo16f(ul2), v2y = hi16f(uh2) + hi16f(ul2);
      float v3x = lo16f(uh3) + lo16f(ul3), v3y = hi16f(uh3) + hi16f(ul3);
      int t;
      t = pk0 >> 18;
      if (t == 0) { a0x += v0x; a0y += v0y; } else if (t == 1) { a1x += v0x; a1y += v0y; }
      else if (t == 2) { a2x += v0x; a2y += v0y; } else { a3x += v0x; a3y += v0y; }
      t = pk1 >> 18;
      if (t == 0) { a0x += v1x; a0y += v1y; } else if (t == 1) { a1x += v1x; a1y += v1y; }
      else if (t == 2) { a2x += v1x; a2y += v1y; } else { a3x += v1x; a3y += v1y; }
      t = pk2 >> 18;
      if (t == 0) { a0x += v2x; a0y += v2y; } else if (t == 1) { a1x += v2x; a1y += v2y; }
      else if (t == 2) { a2x += v2x; a2y += v2y; } else { a3x += v2x; a3y += v2y; }
      t = pk3 >> 18;
      if (t == 0) { a0x += v3x; a0y += v3y; } else if (t == 1) { a1x += v3x; a1y += v3y; }
      else if (t == 2) { a2x += v3x; a2y += v3y; } else { a3x += v3x; a3y += v3y; }
    }
    for (; i < cnt; ++i) {
      int pk = __shfl(mypk, i);
      unsigned uh = hhiU[(size_t)(pk & 0x3ffff) * 64 + lane];
      unsigned ul = hloU[(size_t)(pk & 0x3ffff) * 64 + lane];
      float vx = lo16f(uh) + lo16f(ul), vy = hi16f(uh) + hi16f(ul);
      int t = pk >> 18;
      if (t == 0) { a0x += vx; a0y += vy; } else if (t == 1) { a1x += vx; a1y += vy; }
      else if (t == 2) { a2x += vx; a2y += vy; } else { a3x += vx; a3y += vy; }
    }
  }
  size_t bu = (size_t)local * 256 + lane;
  unsigned short h0, l0, h1, l1;
  split2(a0x, h0, l0); split2(a0y, h1, l1);
  A3hiU[bu] = (unsigned)h0 | ((unsigned)h1 << 16);
  A3loU[bu] = (unsigned)l0 | ((unsigned)l1 << 16);
  split2(a1x, h0, l0); split2(a1y, h1, l1);
  A3hiU[bu + 64] = (unsigned)h0 | ((unsigned)h1 << 16);
  A3loU[bu + 64] = (unsigned)l0 | ((unsigned)l1 << 16);
  split2(a2x, h0, l0); split2(a2y, h1, l1);
  A3hiU[bu + 128] = (unsigned)h0 | ((unsigned)h1 << 16);
  A3loU[bu + 128] = (unsigned)l0 | ((unsigned)l1 << 16);
  split2(a3x, h0, l0); split2(a3y, h1, l1);
  A3hiU[bu + 192] = (unsigned)h0 | ((unsigned)h1 << 16);
  A3loU[bu + 192] = (unsigned)l0 | ((unsigned)l1 << 16);
}

// ---------- MFMA GEMM (a-computation): C = A3 @ WlT^T + deg-bias, split store ----------
__global__ __launch_bounds__(256) void k_gemm_a(
    const unsigned short* __restrict__ Ahi, const unsigned short* __restrict__ Alo,
    const unsigned short* __restrict__ Whi, const unsigned short* __restrict__ Wlo,
    const float* __restrict__ bias, const int* __restrict__ deg4,
    unsigned short* __restrict__ Chi, unsigned short* __restrict__ Clo, int n) {
  int wid = threadIdx.x >> 6, lane = threadIdx.x & 63;
  int rowbase = blockIdx.x * 64 + (wid >> 1) * 32;
  int colbase = blockIdx.y * 64 + (wid & 1) * 32;
  int lr = lane & 15, lk = lane >> 4;
  f32x4 acc[2][2];
  #pragma unroll
  for (int nn = 0; nn < 2; ++nn)
    #pragma unroll
    for (int mm = 0; mm < 2; ++mm) acc[mm][nn] = (f32x4){0.f, 0.f, 0.f, 0.f};
  for (int k0 = 0; k0 < 512; k0 += 32) {
    int koff = k0 + lk * 8;
    short8v ah[2], al[2], bh[2], bl[2];
    #pragma unroll
    for (int mm = 0; mm < 2; ++mm) {
      size_t off = (size_t)(rowbase + mm * 16 + lr) * 512 + koff;
      ah[mm] = *(const short8v*)(Ahi + off);
      al[mm] = *(const short8v*)(Alo + off);
    }
    #pragma unroll
    for (int nn = 0; nn < 2; ++nn) {
      size_t off = (size_t)(colbase + nn * 16 + lr) * 512 + koff;
      bh[nn] = *(const short8v*)(Whi + off);
      bl[nn] = *(const short8v*)(Wlo + off);
    }
    #pragma unroll
    for (int mm = 0; mm < 2; ++mm)
      #pragma unroll
      for (int nn = 0; nn < 2; ++nn) {
        acc[mm][nn] = __builtin_amdgcn_mfma_f32_16x16x32_bf16(ah[mm], bh[nn], acc[mm][nn], 0, 0, 0);
        acc[mm][nn] = __builtin_amdgcn_mfma_f32_16x16x32_bf16(ah[mm], bl[nn], acc[mm][nn], 0, 0, 0);
        acc[mm][nn] = __builtin_amdgcn_mfma_f32_16x16x32_bf16(al[mm], bh[nn], acc[mm][nn], 0, 0, 0);
      }
  }
  #pragma unroll
  for (int mm = 0; mm < 2; ++mm) {
    #pragma unroll
    for (int j = 0; j < 4; ++j) {
      int row = rowbase + mm * 16 + lk * 4 + j;
      if (row < n) {
        int4 dg = *(const int4*)(deg4 + (size_t)row * 4);
        #pragma unroll
        for (int nn = 0; nn < 2; ++nn) {
          int col = colbase + nn * 16 + lr;
          float v = acc[mm][nn][j] + dg.x * bias[col] + dg.y * bias[128 + col]
                  + dg.z * bias[256 + col] + dg.w * bias[384 + col];
          unsigned short hi, lo; split2(v, hi, lo);
          Chi[(size_t)row * DD + col] = hi;
          Clo[(size_t)row * DD + col] = lo;
        }
      }
    }
  }
}

// ---------- fused GRU: gi+gh GEMMs + gate math, writes h' split planes ----------
__global__ __launch_bounds__(256) void k_grufuse(
    const unsigned short* __restrict__ Ahi, const unsigned short* __restrict__ Alo,
    const unsigned short* __restrict__ Hhi, const unsigned short* __restrict__ Hlo,
    const unsigned short* __restrict__ WihH, const unsigned short* __restrict__ WihL,
    const unsigned short* __restrict__ WhhH, const unsigned short* __restrict__ WhhL,
    const float* __restrict__ bih, const float* __restrict__ bhh,
    unsigned short* __restrict__ Ohi, unsigned short* __restrict__ Olo,
    int nbase, int cc) {
  int wid = threadIdx.x >> 6, lane = threadIdx.x & 63;
  int rb = blockIdx.x * 64 + (wid & 1) * 32;    // chunk-local row base
  int cb = blockIdx.y * 64 + (wid >> 1) * 32;   // d col base
  int lr = lane & 15, lk = lane >> 4;
  f32x4 sr[2][2], sz[2][2], gn[2][2], hn[2][2];
  #pragma unroll
  for (int nn = 0; nn < 2; ++nn) {
    int col = cb + nn * 16 + lr;
    float br = bih[col] + bhh[col];
    float bz = bih[DD + col] + bhh[DD + col];
    float bi = bih[2 * DD + col];
    float bh = bhh[2 * DD + col];
    #pragma unroll
    for (int mm = 0; mm < 2; ++mm) {
      sr[mm][nn] = (f32x4){br, br, br, br};
      sz[mm][nn] = (f32x4){bz, bz, bz, bz};
      gn[mm][nn] = (f32x4){bi, bi, bi, bi};
      hn[mm][nn] = (f32x4){bh, bh, bh, bh};
    }
  }
  for (int k0 = 0; k0 < DD; k0 += 32) {
    int koff = k0 + lk * 8;
    short8v ah[2], al[2], hh_[2], hl_[2];
    #pragma unroll
    for (int mm = 0; mm < 2; ++mm) {
      size_t ao = (size_t)(rb + mm * 16 + lr) * DD + koff;
      ah[mm] = *(const short8v*)(Ahi + ao);
      al[mm] = *(const short8v*)(Alo + ao);
      size_t ho = (size_t)(nbase + rb + mm * 16 + lr) * DD + koff;
      hh_[mm] = *(const short8v*)(Hhi + ho);
      hl_[mm] = *(const short8v*)(Hlo + ho);
    }
    #pragma unroll
    for (int nn = 0; nn < 2; ++nn) {
      int c16 = cb + nn * 16 + lr;
      {  // r gate
        short8v wiH = *(const short8v*)(WihH + (size_t)c16 * DD + koff);
        short8v wiL = *(const short8v*)(WihL + (size_t)c16 * DD + koff);
        short8v whH = *(const short8v*)(WhhH + (size_t)c16 * DD + koff);
        short8v whL = *(const short8v*)(WhhL + (size_t)c16 * DD + koff);
        #pragma unroll
        for (int mm = 0; mm < 2; ++mm) {
          sr[mm][nn] = __builtin_amdgcn_mfma_f32_16x16x32_bf16(ah[mm], wiH, sr[mm][nn], 0, 0, 0);
          sr[mm][nn] = __builtin_amdgcn_mfma_f32_16x16x32_bf16(ah[mm], wiL, sr[mm][nn], 0, 0, 0);
          sr[mm][nn] = __builtin_amdgcn_mfma_f32_16x16x32_bf16(al[mm], wiH, sr[mm][nn], 0, 0, 0);
          sr[mm][nn] = __builtin_amdgcn_mfma_f32_16x16x32_bf16(hh_[mm], whH, sr[mm][nn], 0, 0, 0);
          sr[mm][nn] = __builtin_amdgcn_mfma_f32_16x16x32_bf16(hh_[mm], whL, sr[mm][nn], 0, 0, 0);
          sr[mm][nn] = __builtin_amdgcn_mfma_f32_16x16x32_bf16(hl_[mm], whH, sr[mm][nn], 0, 0, 0);
        }
      }
      {  // z gate
        int rz = DD + c16;
        short8v wiH = *(const short8v*)(WihH + (size_t)rz * DD + koff);
        short8v wiL = *(const short8v*)(WihL + (size_t)rz * DD + koff);
        short8v whH = *(const short8v*)(WhhH + (size_t)rz * DD + koff);
        short8v whL = *(const short8v*)(WhhL + (size_t)rz * DD + koff);
        #pragma unroll
        for (int mm = 0; mm < 2; ++mm) {
          sz[mm][nn] = __builtin_amdgcn_mfma_f32_16x16x32_bf16(ah[mm], wiH, sz[mm][nn], 0, 0, 0);
          sz[mm][nn] = __builtin_amdgcn_mfma_f32_16x16x32_bf16(ah[mm], wiL, sz[mm][nn], 0, 0, 0);
          sz[mm][nn] = __builtin_amdgcn_mfma_f32_16x16x32_bf16(al[mm], wiH, sz[mm][nn], 0, 0, 0);
          sz[mm][nn] = __builtin_amdgcn_mfma_f32_16x16x32_bf16(hh_[mm], whH, sz[mm][nn], 0, 0, 0);
          sz[mm][nn] = __builtin_amdgcn_mfma_f32_16x16x32_bf16(hh_[mm], whL, sz[mm][nn], 0, 0, 0);
          sz[mm][nn] = __builtin_amdgcn_mfma_f32_16x16x32_bf16(hl_[mm], whH, sz[mm][nn], 0, 0, 0);
        }
      }
      {  // n gate
        int rn = 2 * DD + c16;
        short8v wiH = *(const short8v*)(WihH + (size_t)rn * DD + koff);
        short8v wiL = *(const short8v*)(WihL + (size_t)rn * DD + koff);
        short8v whH = *(const short8v*)(WhhH + (size_t)rn * DD + koff);
        short8v whL = *(const short8v*)(WhhL + (size_t)rn * DD + koff);
        #pragma unroll
        for (int mm = 0; mm < 2; ++mm) {
          gn[mm][nn] = __builtin_amdgcn_mfma_f32_16x16x32_bf16(ah[mm], wiH, gn[mm][nn], 0, 0, 0);
          gn[mm][nn] = __builtin_amdgcn_mfma_f32_16x16x32_bf16(ah[mm], wiL, gn[mm][nn], 0, 0, 0);
          gn[mm][nn] = __builtin_amdgcn_mfma_f32_16x16x32_bf16(al[mm], wiH, gn[mm][nn], 0, 0, 0);
          hn[mm][nn] = __builtin_amdgcn_mfma_f32_16x16x32_bf16(hh_[mm], whH, hn[mm][nn], 0, 0, 0);
          hn[mm][nn] = __builtin_amdgcn_mfma_f32_16x16x32_bf16(hh_[mm], whL, hn[mm][nn], 0, 0, 0);
          hn[mm][nn] = __builtin_amdgcn_mfma_f32_16x16x32_bf16(hl_[mm], whH, hn[mm][nn], 0, 0, 0);
        }
      }
    }
  }
  #pragma unroll
  for (int mm = 0; mm < 2; ++mm) {
    #pragma unroll
    for (int j = 0; j < 4; ++j) {
      int row = rb + mm * 16 + lk * 4 + j;
      if (row < cc) {
        #pragma unroll
        for (int nn = 0; nn < 2; ++nn) {
          int col = cb + nn * 16 + lr;
          float r = 1.f / (1.f + expf(-sr[mm][nn][j]));
          float z = 1.f / (1.f + expf(-sz[mm][nn][j]));
          float nt = tanhf(gn[mm][nn][j] + r * hn[mm][nn][j]);
          size_t gidx = (size_t)(nbase + row) * DD + col;
          float hv = (1.f - z) * nt + z * rec2(Hhi, Hlo, gidx);
          unsigned short uh, ul; split2(hv, uh, ul);
          Ohi[gidx] = uh; Olo[gidx] = ul;
        }
      }
    }
  }
}

// ---------- weight prep ----------
__global__ void k_repack_wlin(const float* __restrict__ W,
    unsigned short* __restrict__ hi_, unsigned short* __restrict__ lo_) {
  int idx = blockIdx.x * blockDim.x + threadIdx.x;
  if (idx >= 128 * 512) return;
  int o = idx >> 9, kd = idx & 511;
  int k = kd >> 7, d = kd & 127;
  float v = W[k * 16384 + o * 128 + d];
  unsigned short h, l; split2(v, h, l);
  hi_[idx] = h; lo_[idx] = l;
}

__global__ void k_splitw(const float* __restrict__ x,
    unsigned short* __restrict__ hi_, unsigned short* __restrict__ lo_, int n) {
  int i = blockIdx.x * blockDim.x + threadIdx.x;
  if (i >= n) return;
  unsigned short h, l; split2(x[i], h, l);
  hi_[i] = h; lo_[i] = l;
}

// ---------- readout ----------
__global__ void k_gate(const unsigned short* __restrict__ hhi,
    const unsigned short* __restrict__ hlo, const float* __restrict__ ann,
    const float* __restrict__ gw, const float* __restrict__ gb,
    float* __restrict__ gate, int n) {
  int gt = blockIdx.x * blockDim.x + threadIdx.x;
  int wv = gt >> 6;
  int lane = threadIdx.x & 63;
  if (wv >= n) return;
  float p = rec2(hhi, hlo, (size_t)wv * DD + lane) * gw[lane]
          + rec2(hhi, hlo, (size_t)wv * DD + 64 + lane) * gw[64 + lane]
          + ann[(size_t)wv * ANND + lane] * gw[128 + lane];
  for (int off = 32; off; off >>= 1) p += __shfl_down(p, off);
  if (lane == 0) gate[wv] = p + gb[0];
}

// sorted node2graph -> segment bounds via boundary detection (no atomics)
__global__ void k_bounds(const int* __restrict__ n2g, int* __restrict__ startg,
    int* __restrict__ endg, int n) {
  int i = blockIdx.x * blockDim.x + threadIdx.x;
  if (i >= n) return;
  int g = n2g[i];
  if (i == 0 || n2g[i - 1] != g) startg[g] = i;
  if (i == n - 1 || n2g[i + 1] != g) endg[g] = i + 1;
}

// per-graph softmax max + 1/denominator
__global__ __launch_bounds__(256) void k_mden(const float* __restrict__ gate,
    const int* __restrict__ startg, const int* __restrict__ endg,
    float* __restrict__ mg, float* __restrict__ invg) {
  __shared__ float red[256];
  int g = blockIdx.x;
  int s = startg[g], e = endg[g];
  int tid = threadIdx.x;
  float m = -1e30f;
  for (int i = s + tid; i < e; i += 256) m = fmaxf(m, gate[i]);
  red[tid] = m; __syncthreads();
  for (int off = 128; off; off >>= 1) {
    if (tid < off) red[tid] = fmaxf(red[tid], red[tid + off]);
    __syncthreads();
  }
  m = red[0];
  __syncthreads();
  float sum = 0.f;
  for (int i = s + tid; i < e; i += 256) sum += expf(gate[i] - m);
  red[tid] = sum; __syncthreads();
  for (int off = 128; off; off >>= 1) {
    if (tid < off) red[tid] += red[tid + off];
    __syncthreads();
  }
  if (tid == 0) { mg[g] = m; invg[g] = (s < e) ? 1.f / red[0] : 0.f; }
}

// weighted readout; grid (B, 2): y=0 h-dims (packed uint pairs), y=1 ann-dims
__global__ __launch_bounds__(256) void k_pool2(const float* __restrict__ gate,
    const unsigned* __restrict__ hhiU, const unsigned* __restrict__ hloU,
    const float* __restrict__ ann, const int* __restrict__ startg,
    const int* __restrict__ endg, const float* __restrict__ mg,
    const float* __restrict__ invg, float* __restrict__ readout) {
  __shared__ float redx[256], redy[256];
  int g = blockIdx.x;
  int s = startg[g], e = endg[g];
  int nl = threadIdx.x >> 6, lane = threadIdx.x & 63;
  float m = mg[g], inv = invg[g];
  if (blockIdx.y == 0) {
    float ax = 0.f, ay = 0.f;
    for (int i = s + nl; i < e; i += 4) {
      float al = expf(gate[i] - m) * inv;
      unsigned uh = hhiU[(size_t)i * 64 + lane];
      unsigned ul = hloU[(size_t)i * 64 + lane];
      ax += al * (lo16f(uh) + lo16f(ul));
      ay += al * (hi16f(uh) + hi16f(ul));
    }
    redx[threadIdx.x] = ax; redy[threadIdx.x] = ay;
    __syncthreads();
    if (nl == 0) {
      float sx = redx[lane] + redx[64 + lane] + redx[128 + lane] + redx[192 + lane];
      float sy = redy[lane] + redy[64 + lane] + redy[128 + lane] + redy[192 + lane];
      readout[g * (DD + ANND) + 2 * lane] = sx;
      readout[g * (DD + ANND) + 2 * lane + 1] = sy;
    }
  } else {
    float acc = 0.f;
    for (int i = s + nl; i < e; i += 4) {
      float al = expf(gate[i] - m) * inv;
      acc += al * ann[(size_t)i * ANND + lane];
    }
    redx[threadIdx.x] = acc;
    __syncthreads();
    if (nl == 0)
      readout[g * (DD + ANND) + DD + lane] =
          redx[lane] + redx[64 + lane] + redx[128 + lane] + redx[192 + lane];
  }
}

__global__ void k_logits(const float* __restrict__ readout, const float* __restrict__ ow,
    const float* __restrict__ ob, const int* __restrict__ labels,
    float* __restrict__ out, int B) {
  __shared__ float lsum[64];
  int g = threadIdx.x;
  float loss_c = 0.f;
  if (g < B) {
    float lg[NCLS];
    float mx = -1e30f;
    int best = 0;
    for (int c = 0; c < NCLS; ++c) {
      float acc = ob[c];
      const float* r = readout + g * (DD + ANND);
      const float* w = ow + c * (DD + ANND);
      for (int d = 0; d < DD + ANND; ++d) acc += r[d] * w[d];
      lg[c] = acc;
      if (acc > mx) { mx = acc; best = c; }
    }
    float se = 0.f;
    for (int c = 0; c < NCLS; ++c) se += expf(lg[c] - mx);
    float lse = mx + logf(se);
    loss_c = -(lg[labels[g]] - lse);
    out[1 + g] = (float)best;
  }
  lsum[threadIdx.x] = loss_c;
  __syncthreads();
  for (int off = 32; off; off >>= 1) {
    if (threadIdx.x < off) lsum[threadIdx.x] += lsum[threadIdx.x + off];
    __syncthreads();
  }
  if (threadIdx.x == 0) out[0] = lsum[0] / (float)B;
}

extern "C" void kernel_launch(void* const* d_in, const int* in_sizes, int n_in,
                              void* d_out, int out_size, void* d_ws, size_t ws_size,
                              hipStream_t stream) {
  const float* annotation = (const float*)d_in[0];
  const int*   src        = (const int*)d_in[1];
  const int*   dst        = (const int*)d_in[2];
  const int*   et         = (const int*)d_in[3];
  const int*   n2g        = (const int*)d_in[4];
  const int*   labels     = (const int*)d_in[5];
  const float* W_lin      = (const float*)d_in[6];
  const float* b_lin      = (const float*)d_in[7];
  const float* W_ih       = (const float*)d_in[8];
  const float* W_hh       = (const float*)d_in[9];
  const float* b_ih       = (const float*)d_in[10];
  const float* b_hh       = (const float*)d_in[11];
  const float* gate_w     = (const float*)d_in[12];
  const float* gate_b     = (const float*)d_in[13];
  const float* out_w      = (const float*)d_in[14];
  const float* out_b      = (const float*)d_in[15];

  int N = in_sizes[0] / ANND;
  int E = in_sizes[1];
  int B = in_sizes[5];
  int Np = (N + 63) & ~63;

  // ---- workspace budget: fixed allocations, then largest chunk that fits ----
  auto rup = [](size_t b) { return (b + 255) & ~(size_t)255; };
  size_t fixed = 0;
  fixed += 4 * rup((size_t)Np * DD * 2);           // h ping-pong planes
  fixed += rup((size_t)N * 4);                     // gate
  fixed += rup((size_t)B * (DD + ANND) * 4);       // readout
  fixed += 2 * rup((size_t)B * 4);                 // startg, endg
  fixed += 2 * rup((size_t)B * 4);                 // mg, invg
  fixed += rup((size_t)(N + 1) * 4);               // base
  fixed += rup((size_t)N * 4);                     // cursor
  fixed += rup((size_t)N * 16);                    // deg4
  fixed += rup((size_t)E * 4);                     // cpack
  fixed += 2 * rup(128 * 512 * 2) + 4 * rup(384 * 128 * 2);  // weights
  size_t slack = 1 << 20;
  size_t avail = (ws_size > fixed + slack) ? ws_size - fixed - slack : 0;
  long long ch = (long long)(avail / 2560);        // A3 + a planes per node
  int CH = (int)((ch / 64) * 64);
  if (CH < 64) CH = 64;
  if (CH > Np) CH = Np;

  char* wsP = (char*)d_ws;
  auto alloc = [&](size_t bytes) -> void* {
    void* p = (void*)wsP;
    wsP += (bytes + 255) & ~(size_t)255;
    return p;
  };
  unsigned short* hP_hi[2], *hP_lo[2];
  hP_hi[0] = (unsigned short*)alloc((size_t)Np * DD * 2);
  hP_lo[0] = (unsigned short*)alloc((size_t)Np * DD * 2);
  hP_hi[1] = (unsigned short*)alloc((size_t)Np * DD * 2);
  hP_lo[1] = (unsigned short*)alloc((size_t)Np * DD * 2);
  float* gate = (float*)alloc((size_t)N * 4);
  float* readout = (float*)alloc((size_t)B * (DD + ANND) * 4);
  int* startg = (int*)alloc((size_t)B * 4);
  int* endg   = (int*)alloc((size_t)B * 4);
  float* mg   = (float*)alloc((size_t)B * 4);
  float* invg = (float*)alloc((size_t)B * 4);
  int* base   = (int*)alloc((size_t)(N + 1) * 4);
  int* cursor = (int*)alloc((size_t)N * 4);
  int* deg4   = (int*)alloc((size_t)N * 16);
  int* cpack  = (int*)alloc((size_t)E * 4);
  unsigned short* WlT_hi = (unsigned short*)alloc(128 * 512 * 2);
  unsigned short* WlT_lo = (unsigned short*)alloc(128 * 512 * 2);
  unsigned short* Wih_hi = (unsigned short*)alloc(384 * 128 * 2);
  unsigned short* Wih_lo = (unsigned short*)alloc(384 * 128 * 2);
  unsigned short* Whh_hi = (unsigned short*)alloc(384 * 128 * 2);
  unsigned short* Whh_lo = (unsigned short*)alloc(384 * 128 * 2);
  unsigned short* A3hi = (unsigned short*)alloc((size_t)CH * 512 * 2);
  unsigned short* A3lo = (unsigned short*)alloc((size_t)CH * 512 * 2);
  unsigned short* a_hi = (unsigned short*)alloc((size_t)CH * DD * 2);
  unsigned short* a_lo = (unsigned short*)alloc((size_t)CH * DD * 2);

  // init + CSR + weight prep (once per launch)
  k_init<<<(Np * DD + 255) / 256, 256, 0, stream>>>(annotation, hP_hi[0], hP_lo[0], N, Np);
  hipMemsetAsync(cursor, 0, (size_t)N * 4, stream);
  hipMemsetAsync(deg4, 0, (size_t)N * 16, stream);
  hipMemsetAsync(startg, 0x7f, (size_t)B * 4, stream);
  hipMemsetAsync(endg, 0, (size_t)B * 4, stream);
  k_deg4<<<(E + 255) / 256, 256, 0, stream>>>(dst, et, deg4, E);
  k_scan<<<1, 1024, 0, stream>>>(deg4, base, N);
  k_place<<<(E + 255) / 256, 256, 0, stream>>>(src, dst, et, base, cursor, cpack, E);
  k_bounds<<<(N + 255) / 256, 256, 0, stream>>>(n2g, startg, endg, N);
  k_repack_wlin<<<(128 * 512 + 255) / 256, 256, 0, stream>>>(W_lin, WlT_hi, WlT_lo);
  k_splitw<<<(384 * 128 + 255) / 256, 256, 0, stream>>>(W_ih, Wih_hi, Wih_lo, 384 * 128);
  k_splitw<<<(384 * 128 + 255) / 256, 256, 0, stream>>>(W_hh, Whh_hi, Whh_lo, 384 * 128);

  int cur = 0;
  for (int s = 0; s < NSTEPS; ++s) {
    int nxt = cur ^ 1;
    for (int nbase = 0; nbase < N; nbase += CH) {
      int cc = min(CH, N - nbase);
      int cgrid = (cc + 63) / 64;
      k_aggh<<<(cc + 3) / 4, 256, 0, stream>>>(
          (const unsigned*)hP_hi[cur], (const unsigned*)hP_lo[cur], base, cpack,
          (unsigned*)A3hi, (unsigned*)A3lo, nbase, cc);
      k_gemm_a<<<dim3(cgrid, 2), 256, 0, stream>>>(A3hi, A3lo,
          WlT_hi, WlT_lo, b_lin, deg4 + (size_t)nbase * 4, a_hi, a_lo, cc);
      k_grufuse<<<dim3(cgrid, 2), 256, 0, stream>>>(a_hi, a_lo,
          hP_hi[cur], hP_lo[cur], Wih_hi, Wih_lo, Whh_hi, Whh_lo,
          b_ih, b_hh, hP_hi[nxt], hP_lo[nxt], nbase, cc);
    }
    cur ^= 1;
  }

  k_gate<<<(N * 64 + 255) / 256, 256, 0, stream>>>(
      hP_hi[cur], hP_lo[cur], annotation, gate_w, gate_b, gate, N);
  k_mden<<<B, 256, 0, stream>>>(gate, startg, endg, mg, invg);
  k_pool2<<<dim3(B, 2), 256, 0, stream>>>(gate, (const unsigned*)hP_hi[cur],
      (const unsigned*)hP_lo[cur], annotation, startg, endg, mg, invg, readout);
  k_logits<<<1, 64, 0, stream>>>(readout, out_w, out_b, labels, (float*)d_out, B);
}